// Round 12
// baseline (248.377 us; speedup 1.0000x reference)
//
#include <hip/hip_runtime.h>
#include <stdint.h>

typedef __attribute__((ext_vector_type(8))) __bf16 bf16x8;
typedef __attribute__((ext_vector_type(4))) float f32x4;
typedef __attribute__((ext_vector_type(4))) unsigned short us4;
typedef __attribute__((ext_vector_type(8))) unsigned short us8v;

__device__ __forceinline__ unsigned short f2b(float f){
  unsigned int u = __builtin_bit_cast(unsigned int, f);
  unsigned int r = (u + 0x7fffu + ((u >> 16) & 1u)) >> 16;
  return (unsigned short)r;
}
// fast round-biased f32->bf16 (error <= 2^-9, used for P only)
__device__ __forceinline__ unsigned short f2b_fast(float f){
  unsigned int u = __builtin_bit_cast(unsigned int, f);
  return (unsigned short)((u + 0x8000u) >> 16);
}
__device__ __forceinline__ float b2f(unsigned short h){
  unsigned int u = ((unsigned int)h) << 16;
  return __builtin_bit_cast(float, u);
}

#define KDIM 1024

// ---------------- fused prep: x cast + 5 LDS-tiled transposes ----------------
__global__ __launch_bounds__(256) void k_prep(
    const float* __restrict__ x,   unsigned short* __restrict__ Xbf,
    const float* __restrict__ fqk, unsigned short* __restrict__ FqkT,
    const float* __restrict__ fv,  unsigned short* __restrict__ FvT,
    const float* __restrict__ rqk, unsigned short* __restrict__ RqkT,
    const float* __restrict__ rv,  unsigned short* __restrict__ RvT,
    const float* __restrict__ wo,  unsigned short* __restrict__ WOT)
{
  __shared__ float tile[32][33];
  int blk = blockIdx.x;
  int tid = threadIdx.x;
  if (blk < 4096){
    int idx = blk * 256 + tid;
    float4 v = ((const float4*)x)[idx];
    us4 o; o.x = f2b(v.x); o.y = f2b(v.y); o.z = f2b(v.z); o.w = f2b(v.w);
    ((us4*)Xbf)[idx] = o;
    return;
  }
  int t = blk - 4096;
  int mid = t >> 10;
  int within = t & 1023;
  const float* src; unsigned short* dst;
  int b, R, C, tr, tc;
  if (mid < 2){
    src = mid == 0 ? fqk : fv;  dst = mid == 0 ? FqkT : FvT;
    R = 1024; C = 128;
    b = within >> 7; int tw = within & 127; tr = tw >> 2; tc = tw & 3;
  } else {
    src = mid == 2 ? rqk : (mid == 3 ? rv : wo);
    dst = mid == 2 ? RqkT : (mid == 3 ? RvT : WOT);
    R = 1024; C = 1024;
    b = 0; tr = within >> 5; tc = within & 31;
  }
  int r = tid >> 3, c0 = (tid & 7) * 4;
  size_t base = (size_t)b * R * C;
  float4 v = *(const float4*)&src[base + (size_t)(tr*32 + r) * C + tc*32 + c0];
  tile[r][c0+0] = v.x; tile[r][c0+1] = v.y; tile[r][c0+2] = v.z; tile[r][c0+3] = v.w;
  __syncthreads();
  us4 o;
  o.x = f2b(tile[c0+0][r]); o.y = f2b(tile[c0+1][r]);
  o.z = f2b(tile[c0+2][r]); o.w = f2b(tile[c0+3][r]);
  *(us4*)&dst[base + (size_t)(tc*32 + r) * R + tr*32 + c0] = o;
}

// fused mix, us4-vectorized: block = 8 bs x 32 r-quads.
// AH is concatenated [bs][2048]: cols 0..1023 = qk features, 1024..2047 = v features.
__global__ __launch_bounds__(256) void k_mix(const unsigned short* __restrict__ AH,
    const float* __restrict__ fwq, const float* __restrict__ fwk, const float* __restrict__ fwv,
    const float* __restrict__ rwq, const float* __restrict__ rwk, const float* __restrict__ rwv,
    unsigned short* __restrict__ gq, unsigned short* __restrict__ gk, unsigned short* __restrict__ gv){
  int tid = threadIdx.x;
  int lb = tid >> 5, rq = tid & 31;
  int bs = blockIdx.x * 8 + lb;
  const unsigned short* row = AH + (size_t)bs * 2048;
  float fq[8], fk[8], fv8[8], rqw[8], rkw[8], rvw[8];
  #pragma unroll
  for (int n = 0; n < 8; n++){
    fq[n] = fwq[bs*8+n]; fk[n] = fwk[bs*8+n]; fv8[n] = fwv[bs*8+n];
    rqw[n] = rwq[bs*8+n]; rkw[n] = rwk[bs*8+n]; rvw[n] = rwv[bs*8+n];
  }
  float hq[4] = {}, hk[4] = {}, hv[4] = {};
  #pragma unroll
  for (int n = 0; n < 8; n++){
    us4 a = *(const us4*)&row[n*128 + rq*4];
    us4 av = *(const us4*)&row[1024 + n*128 + rq*4];
    #pragma unroll
    for (int j = 0; j < 4; j++){
      float af = b2f(a[j]);
      hq[j] += af * fq[n]; hk[j] += af * fk[n];
      hv[j] += b2f(av[j]) * fv8[n];
    }
  }
  #pragma unroll
  for (int n = 0; n < 8; n++){
    us4 oq, ok, ov;
    #pragma unroll
    for (int j = 0; j < 4; j++){
      oq[j] = f2b(rqw[n] * hq[j]);
      ok[j] = f2b(rkw[n] * hk[j]);
      ov[j] = f2b(rvw[n] * hv[j]);
    }
    *(us4*)&gq[(size_t)bs*1024 + n*128 + rq*4] = oq;
    *(us4*)&gk[(size_t)bs*1024 + n*128 + rq*4] = ok;
    *(us4*)&gv[(size_t)bs*1024 + n*128 + rq*4] = ov;
  }
}

// Vpack [bh][s][64] -> Vtile [bh][t=s/128][dh][128], LDS-tiled coalesced
__global__ __launch_bounds__(256) void k_transpose_v(const unsigned short* __restrict__ Vp,
                                                     unsigned short* __restrict__ Vt){
  __shared__ unsigned short tile[32][36];
  int blk = blockIdx.x;
  int bh = blk >> 7, rem = blk & 127;
  int t = rem >> 3, tl = rem & 7, ts = tl >> 1, td = tl & 1;
  int tid = threadIdx.x;
  int r = tid >> 3, c0 = (tid & 7) * 4;
  us4 v = *(const us4*)&Vp[((size_t)(bh*2048 + t*128 + ts*32 + r)) * 64 + td*32 + c0];
  *(us4*)&tile[r][c0] = v;
  __syncthreads();
  us4 o;
  o.x = tile[c0+0][r]; o.y = tile[c0+1][r]; o.z = tile[c0+2][r]; o.w = tile[c0+3][r];
  *(us4*)&Vt[((size_t)((bh*16 + t)*64 + td*32 + r)) * 128 + ts*32 + c0] = o;
}

// ---------------- GEMM: C[M,ND] = A[M,K] @ Bt[ND,K]^T, bf16 in, f32 acc ----------------

__device__ __forceinline__ void load_lds16(const void* g, void* l){
  __builtin_amdgcn_global_load_lds((const __attribute__((address_space(1))) unsigned int*)g,
                                   (__attribute__((address_space(3))) unsigned int*)l, 16, 0, 0);
}

template<int OUT_MODE, int BN, int ND, int NTILE>
__global__ __launch_bounds__(256) void k_gemm_bt3(
    const unsigned short* __restrict__ A0, const unsigned short* __restrict__ B0, void* __restrict__ C0,
    const unsigned short* __restrict__ A1, const unsigned short* __restrict__ B1, void* __restrict__ C1,
    const unsigned short* __restrict__ A2, const unsigned short* __restrict__ B2, void* __restrict__ C2)
{
  __shared__ unsigned short Al[2][128*32];
  __shared__ unsigned short Bl[2][BN*32];
  int nb8 = gridDim.x >> 3;
  int swz = (blockIdx.x & 7) * nb8 + (blockIdx.x >> 3);
  int job = swz / NTILE, bid = swz % NTILE;
  const unsigned short* A  = job == 0 ? A0 : (job == 1 ? A1 : A2);
  const unsigned short* Bt = job == 0 ? B0 : (job == 1 ? B1 : B2);
  void* C = job == 0 ? C0 : (job == 1 ? C1 : C2);
  constexpr int NBX = ND / BN;
  int bx = bid % NBX, by = bid / NBX;
  int m0 = by * 128, n0 = bx * BN;
  int tid = threadIdx.x, wid = tid >> 6, lane = tid & 63, l15 = lane & 15, g = lane >> 4;
  int wr = wid >> 1, wc = wid & 1;
  constexpr int WCN = BN / 2;
  constexpr int NACC = WCN / 16;

  auto stage = [&](int buf, int kt){
    #pragma unroll
    for (int i = 0; i < 2; i++){
      int c = i * 256 + tid;
      load_lds16(A + (size_t)(m0 + (c >> 2)) * KDIM + kt * 32 + (c & 3) * 8,
                 &Al[buf][(i * 256 + wid * 64) * 8]);
    }
    #pragma unroll
    for (int i = 0; i < BN/64; i++){
      int c = i * 256 + tid;
      load_lds16(Bt + (size_t)(n0 + (c >> 2)) * KDIM + kt * 32 + (c & 3) * 8,
                 &Bl[buf][(i * 256 + wid * 64) * 8]);
    }
  };

  f32x4 acc[4][NACC] = {};

  stage(0, 0);
  __syncthreads();
  int cur = 0;
  const int nk = KDIM / 32;
  for (int kt = 0; kt < nk; ++kt){
    if (kt + 1 < nk) stage(cur ^ 1, kt + 1);
    bf16x8 af[4], bfv[NACC];
    #pragma unroll
    for (int mi = 0; mi < 4; mi++)
      af[mi] = *(const bf16x8*)&Al[cur][(wr*64 + mi*16 + l15) * 32 + g * 8];
    #pragma unroll
    for (int ni = 0; ni < NACC; ni++)
      bfv[ni] = *(const bf16x8*)&Bl[cur][(wc*WCN + ni*16 + l15) * 32 + g * 8];
    #pragma unroll
    for (int mi = 0; mi < 4; mi++)
      #pragma unroll
      for (int ni = 0; ni < NACC; ni++)
        acc[mi][ni] = __builtin_amdgcn_mfma_f32_16x16x32_bf16(af[mi], bfv[ni], acc[mi][ni], 0, 0, 0);
    __syncthreads();
    cur ^= 1;
  }

  #pragma unroll
  for (int mi = 0; mi < 4; mi++){
    #pragma unroll
    for (int reg = 0; reg < 4; reg++){
      int row = m0 + wr*64 + mi*16 + g*4 + reg;
      #pragma unroll
      for (int ni = 0; ni < NACC; ni++){
        int col = n0 + wc*WCN + ni*16 + l15;
        float v = acc[mi][ni][reg];
        if (OUT_MODE == 0){
          ((float*)C)[(size_t)row * ND + col] = v;
        } else if (OUT_MODE == 1){
          ((unsigned short*)C)[(size_t)row * ND + col] = f2b(v);
        } else {
          int b = row >> 11, s = row & 2047, h = col >> 6, dh = col & 63;
          ((unsigned short*)C)[(((size_t)(b*16 + h)) * 2048 + s) * 64 + dh] = f2b(v);
        }
      }
    }
  }
}

// ---------------- causal flash attention: QBLK=256, 8 waves, chunk=512 split-KV ----------------
// 640 blocks = 8 XCDs x 80 (4 bh x 20 slots each) -> per-XCD L2 holds its 4 heads' K/V.
// Max 8 iters/block (flat tail). Partials (qt>=2) stored bf16-O + f32-l, 33792 B each.
#define PSTR 72
#define PBYTES 33792   // 256*64*2 (O bf16) + 256*4 (l f32), 256-aligned
__global__ __launch_bounds__(512) void k_attn(
    const unsigned short* __restrict__ Qp_, const unsigned short* __restrict__ Kp_,
    const unsigned short* __restrict__ Vt, unsigned short* __restrict__ AO,
    char* __restrict__ Pws)
{
  __shared__ unsigned short Klds[4096];
  __shared__ unsigned short Vlds[4096];
  __shared__ unsigned short Plds[8][32*PSTR];

  int xb = (blockIdx.x & 7) * 80 + (blockIdx.x >> 3);
  int bh = xb / 20;
  int slot = xb % 20;
  int qt = 0, s = slot;
  for (;;){ int ncq = (qt >> 1) + 1; if (s < ncq) break; s -= ncq; qt++; }
  int c = s;
  int nc = (qt >> 1) + 1;
  int b = bh >> 4, h = bh & 15;
  int q0 = qt * 256;
  int kv_lo = c * 512;
  int kv_hi = min((c + 1) * 512, q0 + 256);
  int niter = (kv_hi - kv_lo) >> 6;

  int tid = threadIdx.x, w = tid >> 6, lane = tid & 63, l15 = lane & 15, g = lane >> 4;
  const unsigned short* Qw = Qp_ + ((size_t)bh * 2048 + q0 + w*32) * 64;
  const unsigned short* Kb = Kp_ + (size_t)bh * 2048 * 64;
  const unsigned short* Vb = Vt + (size_t)bh * 16 * 64 * 128;
  unsigned short* Pw = &Plds[w][0];

  int srow = tid >> 3, sj = tid & 7;

  bf16x8 aq[2][2];
  #pragma unroll
  for (int m = 0; m < 2; m++)
    #pragma unroll
    for (int kk = 0; kk < 2; kk++)
      aq[m][kk] = *(const bf16x8*)(Qw + (m*16 + l15)*64 + kk*32 + g*8);

  const float cs = 0.125f;
  float l_run[2][4] = {};
  f32x4 acc_o[2][4] = {};

  us8v kA, vA, kB, vB;

  auto issue = [&](us8v& k0, us8v& v0, int kv0){
    k0 = *(const us8v*)(Kb + ((size_t)(kv0 + srow)) * 64 + sj*8);
    int t128 = kv0 >> 7, koff = kv0 & 64;
    v0 = *(const us8v*)(Vb + ((size_t)(t128*64 + srow)) * 128 + koff + sj*8);
  };
  auto put = [&](us8v k0, us8v v0){
    *(us8v*)&Klds[(sj*64 + srow)*8] = k0;
    *(us8v*)&Vlds[(sj*64 + srow)*8] = v0;
  };
  auto compute = [&](int kv0){
    f32x4 s4[2][4] = {};
    __builtin_amdgcn_s_setprio(1);
    #pragma unroll
    for (int ti = 0; ti < 4; ti++){
      #pragma unroll
      for (int kk = 0; kk < 2; kk++){
        bf16x8 kf = *(const bf16x8*)&Klds[((kk*4 + g)*64 + ti*16 + l15)*8];
        s4[0][ti] = __builtin_amdgcn_mfma_f32_16x16x32_bf16(aq[0][kk], kf, s4[0][ti], 0, 0, 0);
        s4[1][ti] = __builtin_amdgcn_mfma_f32_16x16x32_bf16(aq[1][kk], kf, s4[1][ti], 0, 0, 0);
      }
    }
    __builtin_amdgcn_s_setprio(0);
    bool partial = (kv0 + 64 > q0);
    #pragma unroll
    for (int m = 0; m < 2; m++){
      #pragma unroll
      for (int reg = 0; reg < 4; reg++){
        int row = q0 + w*32 + m*16 + g*4 + reg;
        #pragma unroll
        for (int ti = 0; ti < 4; ti++){
          float x = s4[m][ti][reg] * cs;
          if (partial){
            int col = kv0 + ti*16 + l15;
            if (col > row) x = -1e30f;
          }
          float p = __expf(x);
          l_run[m][reg] += p;
          Pw[(m*16 + g*4 + reg)*PSTR + ((ti ^ g)*16) + l15] = f2b_fast(p);
        }
      }
    }
    bf16x8 pa[2][2];
    #pragma unroll
    for (int m = 0; m < 2; m++)
      #pragma unroll
      for (int cc = 0; cc < 2; cc++){
        int tiL = cc*2 + (g >> 1);
        int tiS = tiL ^ ((l15 >> 2) & 3);
        pa[m][cc] = *(const bf16x8*)&Pw[(m*16 + l15)*PSTR + tiS*16 + (g & 1)*8];
      }
    __builtin_amdgcn_s_setprio(1);
    #pragma unroll
    for (int ni = 0; ni < 4; ni++){
      #pragma unroll
      for (int cc = 0; cc < 2; cc++){
        bf16x8 vf = *(const bf16x8*)&Vlds[((cc*4 + g)*64 + ni*16 + l15)*8];
        acc_o[0][ni] = __builtin_amdgcn_mfma_f32_16x16x32_bf16(pa[0][cc], vf, acc_o[0][ni], 0, 0, 0);
        acc_o[1][ni] = __builtin_amdgcn_mfma_f32_16x16x32_bf16(pa[1][cc], vf, acc_o[1][ni], 0, 0, 0);
      }
    }
    __builtin_amdgcn_s_setprio(0);
  };

  issue(kA, vA, kv_lo);
  put(kA, vA);
  __syncthreads();
  int it = 0;
  while (true){
    bool more = (it + 1 < niter);
    if (more) issue(kB, vB, kv_lo + (it+1)*64);
    compute(kv_lo + it*64);
    ++it;
    if (!more) break;
    __syncthreads();
    put(kB, vB);
    __syncthreads();

    more = (it + 1 < niter);
    if (more) issue(kA, vA, kv_lo + (it+1)*64);
    compute(kv_lo + it*64);
    ++it;
    if (!more) break;
    __syncthreads();
    put(kA, vA);
    __syncthreads();
  }

  #pragma unroll
  for (int m = 0; m < 2; m++)
    #pragma unroll
    for (int reg = 0; reg < 4; reg++){
      #pragma unroll
      for (int off = 1; off < 16; off <<= 1) l_run[m][reg] += __shfl_xor(l_run[m][reg], off);
    }

  if (nc == 1){
    #pragma unroll
    for (int m = 0; m < 2; m++)
      #pragma unroll
      for (int ni = 0; ni < 4; ni++)
        #pragma unroll
        for (int reg = 0; reg < 4; reg++){
          int row = q0 + w*32 + m*16 + g*4 + reg;
          int dh = ni*16 + l15;
          AO[((size_t)(b*2048 + row)) * 1024 + h*64 + dh] = f2b(acc_o[m][ni][reg] / l_run[m][reg]);
        }
  } else {
    int poff = 0;
    for (int q = 2; q < qt; ++q) poff += (q >> 1) + 1;
    char* P0 = Pws + ((size_t)(bh*18 + poff + c)) * PBYTES;
    unsigned short* Ob = (unsigned short*)P0;
    float* lb = (float*)(P0 + 32768);
    #pragma unroll
    for (int m = 0; m < 2; m++)
      #pragma unroll
      for (int ni = 0; ni < 4; ni++)
        #pragma unroll
        for (int reg = 0; reg < 4; reg++){
          int lrow = w*32 + m*16 + g*4 + reg;
          Ob[lrow*64 + ni*16 + l15] = f2b(acc_o[m][ni][reg]);
        }
    if (l15 == 0){
      #pragma unroll
      for (int m = 0; m < 2; m++)
        #pragma unroll
        for (int reg = 0; reg < 4; reg++){
          int lrow = w*32 + m*16 + g*4 + reg;
          lb[lrow] = l_run[m][reg];
        }
    }
  }
}

// combine 2-4 chunks for qt >= 2 (fixed max -> out = sum(O)/sum(l))
__global__ __launch_bounds__(256) void k_attn_reduce(const char* __restrict__ Pws,
                                                     unsigned short* __restrict__ AO){
  int blk = blockIdx.x;                 // 192 = 32 bh x 6 qt
  int bh = blk / 6, qq = blk % 6, qt = qq + 2;
  int b = bh >> 4, h = bh & 15;
  int nc = (qt >> 1) + 1;
  int poff = 0;
  for (int q = 2; q < qt; ++q) poff += (q >> 1) + 1;
  const char* base = Pws + ((size_t)(bh*18 + poff)) * PBYTES;
  int tid = threadIdx.x;
  #pragma unroll 4
  for (int i = 0; i < 64; i++){
    int idx = i*256 + tid;              // row*64 + d
    int row = idx >> 6, d = idx & 63;
    float o = 0.f, l = 0.f;
    for (int cc = 0; cc < nc; ++cc){
      const unsigned short* Oc = (const unsigned short*)(base + (size_t)cc*PBYTES);
      const float* lc = (const float*)(base + (size_t)cc*PBYTES + 32768);
      o += b2f(Oc[idx]);
      l += lc[row];
    }
    AO[((size_t)(b*2048 + qt*256 + row)) * 1024 + h*64 + d] = f2b(o / l);
  }
}

// ---------------- launch ----------------

extern "C" void kernel_launch(void* const* d_in, const int* in_sizes, int n_in,
                              void* d_out, int out_size, void* d_ws, size_t ws_size,
                              hipStream_t stream){
  const float* x    = (const float*)d_in[0];
  const float* fqk  = (const float*)d_in[1];
  const float* fv   = (const float*)d_in[2];
  const float* rqk  = (const float*)d_in[3];
  const float* rv   = (const float*)d_in[4];
  const float* fwQ  = (const float*)d_in[5];
  const float* fwK  = (const float*)d_in[6];
  const float* fwV  = (const float*)d_in[7];
  const float* rwQ  = (const float*)d_in[8];
  const float* rwK  = (const float*)d_in[9];
  const float* rwV  = (const float*)d_in[10];
  const float* wo   = (const float*)d_in[11];
  float* out = (float*)d_out;

  char* ws = (char*)d_ws;
  size_t off = 0;
  auto alloc = [&](size_t bytes)->void*{
    void* p = ws + off; off += (bytes + 255) & ~(size_t)255; return p;
  };
  // weights: FqkT and FvT MUST be contiguous (wide feature GEMM B = [FqkT;FvT])
  unsigned short* FqkT = (unsigned short*)alloc(1024ull*1024*2);
  unsigned short* FvT  = (unsigned short*)alloc(1024ull*1024*2);
  unsigned short* RqkT = (unsigned short*)alloc(1024ull*1024*2);
  unsigned short* RvT  = (unsigned short*)alloc(1024ull*1024*2);
  unsigned short* WOT  = (unsigned short*)alloc(1024ull*1024*2);
  char* overlay = ws + off;
  unsigned short* Xbf  = (unsigned short*)alloc(4096ull*1024*2);
  unsigned short* AHc  = (unsigned short*)alloc(4096ull*2048*2);
  unsigned short* Gq   = (unsigned short*)alloc(4096ull*1024*2);
  unsigned short* Gk   = (unsigned short*)alloc(4096ull*1024*2);
  unsigned short* Gv   = (unsigned short*)alloc(4096ull*1024*2);
  unsigned short* Qp   = (unsigned short*)alloc(4096ull*1024*2);
  unsigned short* Kp   = (unsigned short*)alloc(4096ull*1024*2);
  unsigned short* Vpk  = (unsigned short*)alloc(4096ull*1024*2);
  unsigned short* Vtl  = (unsigned short*)alloc(32ull*16*64*128*2);
  unsigned short* AOm  = (unsigned short*)alloc(4096ull*1024*2);
  char* Pws = overlay;   // 576 partials * 33792 B = 19.5MB, overlays dead region

  k_prep<<<9216, 256, 0, stream>>>(x, Xbf, fqk, FqkT, fv, FvT, rqk, RqkT, rv, RvT, wo, WOT);

  // wide feature GEMM: AHc[4096][2048] = X @ [FqkT;FvT]^T
  k_gemm_bt3<1,128,2048,512><<<512, 256, 0, stream>>>(Xbf, FqkT, AHc,
                                                      nullptr, nullptr, nullptr,
                                                      nullptr, nullptr, nullptr);
  k_mix<<<512, 256, 0, stream>>>(AHc, fwQ, fwK, fwV, rwQ, rwK, rwV, Gq, Gk, Gv);
  // restore GEMMs -> head-packed Q/K/V (3 jobs x 256 tiles)
  k_gemm_bt3<2,128,1024,256><<<768, 256, 0, stream>>>(Gq, RqkT, Qp, Gk, RqkT, Kp, Gv, RvT, Vpk);
  k_transpose_v<<<4096, 256, 0, stream>>>(Vpk, Vtl);
  // causal flash attention (640 blocks x 512 thr, chunk=512)
  k_attn<<<640, 512, 0, stream>>>(Qp, Kp, Vtl, AOm, Pws);
  k_attn_reduce<<<192, 256, 0, stream>>>(Pws, AOm);
  // output projection (BN=64 -> 512 tiles)
  k_gemm_bt3<0,64,1024,512><<<512, 256, 0, stream>>>(AOm, WOT, out,
                                                     nullptr, nullptr, nullptr,
                                                     nullptr, nullptr, nullptr);
}

// Round 13
// 183.919 us; speedup vs baseline: 1.3505x; 1.3505x over previous
//
#include <hip/hip_runtime.h>
#include <stdint.h>

typedef __attribute__((ext_vector_type(8))) __bf16 bf16x8;
typedef __attribute__((ext_vector_type(4))) float f32x4;
typedef __attribute__((ext_vector_type(4))) unsigned short us4;
typedef __attribute__((ext_vector_type(8))) unsigned short us8v;

__device__ __forceinline__ unsigned short f2b(float f){
  unsigned int u = __builtin_bit_cast(unsigned int, f);
  unsigned int r = (u + 0x7fffu + ((u >> 16) & 1u)) >> 16;
  return (unsigned short)r;
}
// fast round-biased f32->bf16 (error <= 2^-9, used for P only)
__device__ __forceinline__ unsigned short f2b_fast(float f){
  unsigned int u = __builtin_bit_cast(unsigned int, f);
  return (unsigned short)((u + 0x8000u) >> 16);
}
__device__ __forceinline__ float b2f(unsigned short h){
  unsigned int u = ((unsigned int)h) << 16;
  return __builtin_bit_cast(float, u);
}

#define KDIM 1024

// ---------------- fused prep: x cast + 5 LDS-tiled transposes ----------------
__global__ __launch_bounds__(256) void k_prep(
    const float* __restrict__ x,   unsigned short* __restrict__ Xbf,
    const float* __restrict__ fqk, unsigned short* __restrict__ FqkT,
    const float* __restrict__ fv,  unsigned short* __restrict__ FvT,
    const float* __restrict__ rqk, unsigned short* __restrict__ RqkT,
    const float* __restrict__ rv,  unsigned short* __restrict__ RvT,
    const float* __restrict__ wo,  unsigned short* __restrict__ WOT)
{
  __shared__ float tile[32][33];
  int blk = blockIdx.x;
  int tid = threadIdx.x;
  if (blk < 4096){
    int idx = blk * 256 + tid;
    float4 v = ((const float4*)x)[idx];
    us4 o; o.x = f2b(v.x); o.y = f2b(v.y); o.z = f2b(v.z); o.w = f2b(v.w);
    ((us4*)Xbf)[idx] = o;
    return;
  }
  int t = blk - 4096;
  int mid = t >> 10;
  int within = t & 1023;
  const float* src; unsigned short* dst;
  int b, R, C, tr, tc;
  if (mid < 2){
    src = mid == 0 ? fqk : fv;  dst = mid == 0 ? FqkT : FvT;
    R = 1024; C = 128;
    b = within >> 7; int tw = within & 127; tr = tw >> 2; tc = tw & 3;
  } else {
    src = mid == 2 ? rqk : (mid == 3 ? rv : wo);
    dst = mid == 2 ? RqkT : (mid == 3 ? RvT : WOT);
    R = 1024; C = 1024;
    b = 0; tr = within >> 5; tc = within & 31;
  }
  int r = tid >> 3, c0 = (tid & 7) * 4;
  size_t base = (size_t)b * R * C;
  float4 v = *(const float4*)&src[base + (size_t)(tr*32 + r) * C + tc*32 + c0];
  tile[r][c0+0] = v.x; tile[r][c0+1] = v.y; tile[r][c0+2] = v.z; tile[r][c0+3] = v.w;
  __syncthreads();
  us4 o;
  o.x = f2b(tile[c0+0][r]); o.y = f2b(tile[c0+1][r]);
  o.z = f2b(tile[c0+2][r]); o.w = f2b(tile[c0+3][r]);
  *(us4*)&dst[base + (size_t)(tc*32 + r) * R + tr*32 + c0] = o;
}

// fused mix, us4-vectorized: block = 8 bs x 32 r-quads.
__global__ __launch_bounds__(256) void k_mix(const unsigned short* __restrict__ AH,
    const float* __restrict__ fwq, const float* __restrict__ fwk, const float* __restrict__ fwv,
    const float* __restrict__ rwq, const float* __restrict__ rwk, const float* __restrict__ rwv,
    unsigned short* __restrict__ gq, unsigned short* __restrict__ gk, unsigned short* __restrict__ gv){
  int tid = threadIdx.x;
  int lb = tid >> 5, rq = tid & 31;
  int bs = blockIdx.x * 8 + lb;
  const unsigned short* row = AH + (size_t)bs * 2048;
  float fq[8], fk[8], fv8[8], rqw[8], rkw[8], rvw[8];
  #pragma unroll
  for (int n = 0; n < 8; n++){
    fq[n] = fwq[bs*8+n]; fk[n] = fwk[bs*8+n]; fv8[n] = fwv[bs*8+n];
    rqw[n] = rwq[bs*8+n]; rkw[n] = rwk[bs*8+n]; rvw[n] = rwv[bs*8+n];
  }
  float hq[4] = {}, hk[4] = {}, hv[4] = {};
  #pragma unroll
  for (int n = 0; n < 8; n++){
    us4 a = *(const us4*)&row[n*128 + rq*4];
    us4 av = *(const us4*)&row[1024 + n*128 + rq*4];
    #pragma unroll
    for (int j = 0; j < 4; j++){
      float af = b2f(a[j]);
      hq[j] += af * fq[n]; hk[j] += af * fk[n];
      hv[j] += b2f(av[j]) * fv8[n];
    }
  }
  #pragma unroll
  for (int n = 0; n < 8; n++){
    us4 oq, ok, ov;
    #pragma unroll
    for (int j = 0; j < 4; j++){
      oq[j] = f2b(rqw[n] * hq[j]);
      ok[j] = f2b(rkw[n] * hk[j]);
      ov[j] = f2b(rvw[n] * hv[j]);
    }
    *(us4*)&gq[(size_t)bs*1024 + n*128 + rq*4] = oq;
    *(us4*)&gk[(size_t)bs*1024 + n*128 + rq*4] = ok;
    *(us4*)&gv[(size_t)bs*1024 + n*128 + rq*4] = ov;
  }
}

// Vpack [bh][s][64] -> Vtile [bh][t=s/128][dh][128], LDS-tiled coalesced
__global__ __launch_bounds__(256) void k_transpose_v(const unsigned short* __restrict__ Vp,
                                                     unsigned short* __restrict__ Vt){
  __shared__ unsigned short tile[32][36];
  int blk = blockIdx.x;
  int bh = blk >> 7, rem = blk & 127;
  int t = rem >> 3, tl = rem & 7, ts = tl >> 1, td = tl & 1;
  int tid = threadIdx.x;
  int r = tid >> 3, c0 = (tid & 7) * 4;
  us4 v = *(const us4*)&Vp[((size_t)(bh*2048 + t*128 + ts*32 + r)) * 64 + td*32 + c0];
  *(us4*)&tile[r][c0] = v;
  __syncthreads();
  us4 o;
  o.x = tile[c0+0][r]; o.y = tile[c0+1][r]; o.z = tile[c0+2][r]; o.w = tile[c0+3][r];
  *(us4*)&Vt[((size_t)((bh*16 + t)*64 + td*32 + r)) * 128 + ts*32 + c0] = o;
}

// ---------------- GEMM: C[M,ND] = A[M,K] @ Bt[ND,K]^T, bf16 in, f32 acc ----------------

__device__ __forceinline__ void load_lds16(const void* g, void* l){
  __builtin_amdgcn_global_load_lds((const __attribute__((address_space(1))) unsigned int*)g,
                                   (__attribute__((address_space(3))) unsigned int*)l, 16, 0, 0);
}

template<int OUT_MODE, int BN, int ND, int NTILE>
__global__ __launch_bounds__(256) void k_gemm_bt3(
    const unsigned short* __restrict__ A0, const unsigned short* __restrict__ B0, void* __restrict__ C0,
    const unsigned short* __restrict__ A1, const unsigned short* __restrict__ B1, void* __restrict__ C1,
    const unsigned short* __restrict__ A2, const unsigned short* __restrict__ B2, void* __restrict__ C2)
{
  __shared__ unsigned short Al[2][128*32];
  __shared__ unsigned short Bl[2][BN*32];
  int nb8 = gridDim.x >> 3;
  int swz = (blockIdx.x & 7) * nb8 + (blockIdx.x >> 3);
  int job = swz / NTILE, bid = swz % NTILE;
  const unsigned short* A  = job == 0 ? A0 : (job == 1 ? A1 : A2);
  const unsigned short* Bt = job == 0 ? B0 : (job == 1 ? B1 : B2);
  void* C = job == 0 ? C0 : (job == 1 ? C1 : C2);
  constexpr int NBX = ND / BN;
  int bx = bid % NBX, by = bid / NBX;
  int m0 = by * 128, n0 = bx * BN;
  int tid = threadIdx.x, wid = tid >> 6, lane = tid & 63, l15 = lane & 15, g = lane >> 4;
  int wr = wid >> 1, wc = wid & 1;
  constexpr int WCN = BN / 2;
  constexpr int NACC = WCN / 16;

  auto stage = [&](int buf, int kt){
    #pragma unroll
    for (int i = 0; i < 2; i++){
      int c = i * 256 + tid;
      load_lds16(A + (size_t)(m0 + (c >> 2)) * KDIM + kt * 32 + (c & 3) * 8,
                 &Al[buf][(i * 256 + wid * 64) * 8]);
    }
    #pragma unroll
    for (int i = 0; i < BN/64; i++){
      int c = i * 256 + tid;
      load_lds16(Bt + (size_t)(n0 + (c >> 2)) * KDIM + kt * 32 + (c & 3) * 8,
                 &Bl[buf][(i * 256 + wid * 64) * 8]);
    }
  };

  f32x4 acc[4][NACC] = {};

  stage(0, 0);
  __syncthreads();
  int cur = 0;
  const int nk = KDIM / 32;
  for (int kt = 0; kt < nk; ++kt){
    if (kt + 1 < nk) stage(cur ^ 1, kt + 1);
    bf16x8 af[4], bfv[NACC];
    #pragma unroll
    for (int mi = 0; mi < 4; mi++)
      af[mi] = *(const bf16x8*)&Al[cur][(wr*64 + mi*16 + l15) * 32 + g * 8];
    #pragma unroll
    for (int ni = 0; ni < NACC; ni++)
      bfv[ni] = *(const bf16x8*)&Bl[cur][(wc*WCN + ni*16 + l15) * 32 + g * 8];
    #pragma unroll
    for (int mi = 0; mi < 4; mi++)
      #pragma unroll
      for (int ni = 0; ni < NACC; ni++)
        acc[mi][ni] = __builtin_amdgcn_mfma_f32_16x16x32_bf16(af[mi], bfv[ni], acc[mi][ni], 0, 0, 0);
    __syncthreads();
    cur ^= 1;
  }

  #pragma unroll
  for (int mi = 0; mi < 4; mi++){
    #pragma unroll
    for (int reg = 0; reg < 4; reg++){
      int row = m0 + wr*64 + mi*16 + g*4 + reg;
      #pragma unroll
      for (int ni = 0; ni < NACC; ni++){
        int col = n0 + wc*WCN + ni*16 + l15;
        float v = acc[mi][ni][reg];
        if (OUT_MODE == 0){
          ((float*)C)[(size_t)row * ND + col] = v;
        } else if (OUT_MODE == 1){
          ((unsigned short*)C)[(size_t)row * ND + col] = f2b(v);
        } else {
          int b = row >> 11, s = row & 2047, h = col >> 6, dh = col & 63;
          ((unsigned short*)C)[(((size_t)(b*16 + h)) * 2048 + s) * 64 + dh] = f2b(v);
        }
      }
    }
  }
}

// ---------------- causal flash attention: QBLK=256, 8 waves, chunk=512 split-KV ----------------
// 640 blocks = 8 XCDs x 80 (4 bh x 20 slots each) -> per-XCD L2 holds its 4 heads' K/V.
// Max 8 iters/block. Partials (qt>=2) stored bf16-O + f32-l, 33792 B each.
#define PSTR 72
#define PBYTES 33792   // 256*64*2 (O bf16) + 256*4 (l f32), 256-aligned
__global__ __launch_bounds__(512) void k_attn(
    const unsigned short* __restrict__ Qp_, const unsigned short* __restrict__ Kp_,
    const unsigned short* __restrict__ Vt, unsigned short* __restrict__ AO,
    char* __restrict__ Pws)
{
  __shared__ unsigned short Klds[4096];
  __shared__ unsigned short Vlds[4096];
  __shared__ unsigned short Plds[8][32*PSTR];

  int xb = (blockIdx.x & 7) * 80 + (blockIdx.x >> 3);
  int bh = xb / 20;
  int slot = xb % 20;
  int qt = 0, s = slot;
  for (;;){ int ncq = (qt >> 1) + 1; if (s < ncq) break; s -= ncq; qt++; }
  int c = s;
  int nc = (qt >> 1) + 1;
  int b = bh >> 4, h = bh & 15;
  int q0 = qt * 256;
  int kv_lo = c * 512;
  int kv_hi = min((c + 1) * 512, q0 + 256);
  int niter = (kv_hi - kv_lo) >> 6;

  int tid = threadIdx.x, w = tid >> 6, lane = tid & 63, l15 = lane & 15, g = lane >> 4;
  const unsigned short* Qw = Qp_ + ((size_t)bh * 2048 + q0 + w*32) * 64;
  const unsigned short* Kb = Kp_ + (size_t)bh * 2048 * 64;
  const unsigned short* Vb = Vt + (size_t)bh * 16 * 64 * 128;
  unsigned short* Pw = &Plds[w][0];

  int srow = tid >> 3, sj = tid & 7;

  bf16x8 aq[2][2];
  #pragma unroll
  for (int m = 0; m < 2; m++)
    #pragma unroll
    for (int kk = 0; kk < 2; kk++)
      aq[m][kk] = *(const bf16x8*)(Qw + (m*16 + l15)*64 + kk*32 + g*8);

  const float cs = 0.125f;
  float l_run[2][4] = {};
  f32x4 acc_o[2][4] = {};

  us8v kA, vA, kB, vB;

  auto issue = [&](us8v& k0, us8v& v0, int kv0){
    k0 = *(const us8v*)(Kb + ((size_t)(kv0 + srow)) * 64 + sj*8);
    int t128 = kv0 >> 7, koff = kv0 & 64;
    v0 = *(const us8v*)(Vb + ((size_t)(t128*64 + srow)) * 128 + koff + sj*8);
  };
  auto put = [&](us8v k0, us8v v0){
    *(us8v*)&Klds[(sj*64 + srow)*8] = k0;
    *(us8v*)&Vlds[(sj*64 + srow)*8] = v0;
  };
  auto compute = [&](int kv0){
    f32x4 s4[2][4] = {};
    __builtin_amdgcn_s_setprio(1);
    #pragma unroll
    for (int ti = 0; ti < 4; ti++){
      #pragma unroll
      for (int kk = 0; kk < 2; kk++){
        bf16x8 kf = *(const bf16x8*)&Klds[((kk*4 + g)*64 + ti*16 + l15)*8];
        s4[0][ti] = __builtin_amdgcn_mfma_f32_16x16x32_bf16(aq[0][kk], kf, s4[0][ti], 0, 0, 0);
        s4[1][ti] = __builtin_amdgcn_mfma_f32_16x16x32_bf16(aq[1][kk], kf, s4[1][ti], 0, 0, 0);
      }
    }
    __builtin_amdgcn_s_setprio(0);
    bool partial = (kv0 + 64 > q0);
    #pragma unroll
    for (int m = 0; m < 2; m++){
      #pragma unroll
      for (int reg = 0; reg < 4; reg++){
        int row = q0 + w*32 + m*16 + g*4 + reg;
        #pragma unroll
        for (int ti = 0; ti < 4; ti++){
          float x = s4[m][ti][reg] * cs;
          if (partial){
            int col = kv0 + ti*16 + l15;
            if (col > row) x = -1e30f;
          }
          float p = __expf(x);
          l_run[m][reg] += p;
          Pw[(m*16 + g*4 + reg)*PSTR + ((ti ^ g)*16) + l15] = f2b_fast(p);
        }
      }
    }
    bf16x8 pa[2][2];
    #pragma unroll
    for (int m = 0; m < 2; m++)
      #pragma unroll
      for (int cc = 0; cc < 2; cc++){
        int tiL = cc*2 + (g >> 1);
        int tiS = tiL ^ ((l15 >> 2) & 3);
        pa[m][cc] = *(const bf16x8*)&Pw[(m*16 + l15)*PSTR + tiS*16 + (g & 1)*8];
      }
    __builtin_amdgcn_s_setprio(1);
    #pragma unroll
    for (int ni = 0; ni < 4; ni++){
      #pragma unroll
      for (int cc = 0; cc < 2; cc++){
        bf16x8 vf = *(const bf16x8*)&Vlds[((cc*4 + g)*64 + ni*16 + l15)*8];
        acc_o[0][ni] = __builtin_amdgcn_mfma_f32_16x16x32_bf16(pa[0][cc], vf, acc_o[0][ni], 0, 0, 0);
        acc_o[1][ni] = __builtin_amdgcn_mfma_f32_16x16x32_bf16(pa[1][cc], vf, acc_o[1][ni], 0, 0, 0);
      }
    }
    __builtin_amdgcn_s_setprio(0);
  };

  issue(kA, vA, kv_lo);
  put(kA, vA);
  __syncthreads();
  int it = 0;
  while (true){
    bool more = (it + 1 < niter);
    if (more) issue(kB, vB, kv_lo + (it+1)*64);
    compute(kv_lo + it*64);
    ++it;
    if (!more) break;
    __syncthreads();
    put(kB, vB);
    __syncthreads();

    more = (it + 1 < niter);
    if (more) issue(kA, vA, kv_lo + (it+1)*64);
    compute(kv_lo + it*64);
    ++it;
    if (!more) break;
    __syncthreads();
    put(kA, vA);
    __syncthreads();
  }

  #pragma unroll
  for (int m = 0; m < 2; m++)
    #pragma unroll
    for (int reg = 0; reg < 4; reg++){
      #pragma unroll
      for (int off = 1; off < 16; off <<= 1) l_run[m][reg] += __shfl_xor(l_run[m][reg], off);
    }

  if (nc == 1){
    #pragma unroll
    for (int m = 0; m < 2; m++)
      #pragma unroll
      for (int ni = 0; ni < 4; ni++)
        #pragma unroll
        for (int reg = 0; reg < 4; reg++){
          int row = q0 + w*32 + m*16 + g*4 + reg;
          int dh = ni*16 + l15;
          AO[((size_t)(b*2048 + row)) * 1024 + h*64 + dh] = f2b(acc_o[m][ni][reg] / l_run[m][reg]);
        }
  } else {
    int poff = 0;
    for (int q = 2; q < qt; ++q) poff += (q >> 1) + 1;
    char* P0 = Pws + ((size_t)(bh*18 + poff + c)) * PBYTES;
    unsigned short* Ob = (unsigned short*)P0;
    float* lb = (float*)(P0 + 32768);
    #pragma unroll
    for (int m = 0; m < 2; m++)
      #pragma unroll
      for (int ni = 0; ni < 4; ni++)
        #pragma unroll
        for (int reg = 0; reg < 4; reg++){
          int lrow = w*32 + m*16 + g*4 + reg;
          Ob[lrow*64 + ni*16 + l15] = f2b(acc_o[m][ni][reg]);
        }
    if (l15 == 0){
      #pragma unroll
      for (int m = 0; m < 2; m++)
        #pragma unroll
        for (int reg = 0; reg < 4; reg++){
          int lrow = w*32 + m*16 + g*4 + reg;
          lb[lrow] = l_run[m][reg];
        }
    }
  }
}

// combine 2-4 chunks for qt >= 2: vectorized, 768 blocks (32bh x 6qt x 4 rowgroups)
__global__ __launch_bounds__(256) void k_attn_reduce(const char* __restrict__ Pws,
                                                     unsigned short* __restrict__ AO){
  int blk = blockIdx.x;
  int rg = blk & 3, tmp = blk >> 2;
  int qq = tmp % 6, bh = tmp / 6;
  int qt = qq + 2;
  int b = bh >> 4, h = bh & 15;
  int nc = (qt >> 1) + 1;
  int poff = 0;
  for (int q = 2; q < qt; ++q) poff += (q >> 1) + 1;
  const char* base = Pws + ((size_t)(bh*18 + poff)) * PBYTES;
  int tid = threadIdx.x;
  int lrow = rg*64 + (tid >> 2);          // 0..255
  int d0 = (tid & 3) * 16;
  float o[16] = {};
  float l = 0.f;
  for (int cc = 0; cc < nc; ++cc){
    const unsigned short* Oc = (const unsigned short*)(base + (size_t)cc*PBYTES);
    const float* lc = (const float*)(base + (size_t)cc*PBYTES + 32768);
    us8v v0 = *(const us8v*)&Oc[lrow*64 + d0];
    us8v v1 = *(const us8v*)&Oc[lrow*64 + d0 + 8];
    #pragma unroll
    for (int j = 0; j < 8; j++){ o[j] += b2f(v0[j]); o[8+j] += b2f(v1[j]); }
    l += lc[lrow];
  }
  float inv = 1.f / l;
  us8v w0, w1;
  #pragma unroll
  for (int j = 0; j < 8; j++){ w0[j] = f2b(o[j]*inv); w1[j] = f2b(o[8+j]*inv); }
  size_t orow = ((size_t)(b*2048 + qt*256 + lrow)) * 1024 + h*64 + d0;
  *(us8v*)&AO[orow] = w0;
  *(us8v*)&AO[orow + 8] = w1;
}

// ---------------- launch ----------------

extern "C" void kernel_launch(void* const* d_in, const int* in_sizes, int n_in,
                              void* d_out, int out_size, void* d_ws, size_t ws_size,
                              hipStream_t stream){
  const float* x    = (const float*)d_in[0];
  const float* fqk  = (const float*)d_in[1];
  const float* fv   = (const float*)d_in[2];
  const float* rqk  = (const float*)d_in[3];
  const float* rv   = (const float*)d_in[4];
  const float* fwQ  = (const float*)d_in[5];
  const float* fwK  = (const float*)d_in[6];
  const float* fwV  = (const float*)d_in[7];
  const float* rwQ  = (const float*)d_in[8];
  const float* rwK  = (const float*)d_in[9];
  const float* rwV  = (const float*)d_in[10];
  const float* wo   = (const float*)d_in[11];
  float* out = (float*)d_out;

  char* ws = (char*)d_ws;
  size_t off = 0;
  auto alloc = [&](size_t bytes)->void*{
    void* p = ws + off; off += (bytes + 255) & ~(size_t)255; return p;
  };
  // weights: FqkT and FvT MUST be contiguous (wide feature GEMM B = [FqkT;FvT])
  unsigned short* FqkT = (unsigned short*)alloc(1024ull*1024*2);
  unsigned short* FvT  = (unsigned short*)alloc(1024ull*1024*2);
  unsigned short* RqkT = (unsigned short*)alloc(1024ull*1024*2);
  unsigned short* RvT  = (unsigned short*)alloc(1024ull*1024*2);
  unsigned short* WOT  = (unsigned short*)alloc(1024ull*1024*2);
  char* overlay = ws + off;
  unsigned short* Xbf  = (unsigned short*)alloc(4096ull*1024*2);
  unsigned short* AHc  = (unsigned short*)alloc(4096ull*2048*2);
  unsigned short* Gq   = (unsigned short*)alloc(4096ull*1024*2);
  unsigned short* Gk   = (unsigned short*)alloc(4096ull*1024*2);
  unsigned short* Gv   = (unsigned short*)alloc(4096ull*1024*2);
  unsigned short* Qp   = (unsigned short*)alloc(4096ull*1024*2);
  unsigned short* Kp   = (unsigned short*)alloc(4096ull*1024*2);
  unsigned short* Vpk  = (unsigned short*)alloc(4096ull*1024*2);
  unsigned short* Vtl  = (unsigned short*)alloc(32ull*16*64*128*2);
  unsigned short* AOm  = (unsigned short*)alloc(4096ull*1024*2);
  char* Pws = overlay;   // 576 partials * 33792 B = 19.5MB, overlays dead region

  k_prep<<<9216, 256, 0, stream>>>(x, Xbf, fqk, FqkT, fv, FvT, rqk, RqkT, rv, RvT, wo, WOT);

  // wide feature GEMM: AHc[4096][2048] = X @ [FqkT;FvT]^T
  k_gemm_bt3<1,128,2048,512><<<512, 256, 0, stream>>>(Xbf, FqkT, AHc,
                                                      nullptr, nullptr, nullptr,
                                                      nullptr, nullptr, nullptr);
  k_mix<<<512, 256, 0, stream>>>(AHc, fwQ, fwK, fwV, rwQ, rwK, rwV, Gq, Gk, Gv);
  // restore GEMMs -> head-packed Q/K/V (3 jobs x 256 tiles)
  k_gemm_bt3<2,128,1024,256><<<768, 256, 0, stream>>>(Gq, RqkT, Qp, Gk, RqkT, Kp, Gv, RvT, Vpk);
  k_transpose_v<<<4096, 256, 0, stream>>>(Vpk, Vtl);
  // causal flash attention (640 blocks x 512 thr, chunk=512)
  k_attn<<<640, 512, 0, stream>>>(Qp, Kp, Vtl, AOm, Pws);
  k_attn_reduce<<<768, 256, 0, stream>>>(Pws, AOm);
  // output projection (BN=64 -> 512 tiles)
  k_gemm_bt3<0,64,1024,512><<<512, 256, 0, stream>>>(AOm, WOT, out,
                                                     nullptr, nullptr, nullptr,
                                                     nullptr, nullptr, nullptr);
}

// Round 14
// 175.525 us; speedup vs baseline: 1.4151x; 1.0478x over previous
//
#include <hip/hip_runtime.h>
#include <stdint.h>

typedef __attribute__((ext_vector_type(8))) __bf16 bf16x8;
typedef __attribute__((ext_vector_type(4))) float f32x4;
typedef __attribute__((ext_vector_type(4))) unsigned short us4;
typedef __attribute__((ext_vector_type(8))) unsigned short us8v;

__device__ __forceinline__ unsigned short f2b(float f){
  unsigned int u = __builtin_bit_cast(unsigned int, f);
  unsigned int r = (u + 0x7fffu + ((u >> 16) & 1u)) >> 16;
  return (unsigned short)r;
}
// fast round-biased f32->bf16 (error <= 2^-9, used for P only)
__device__ __forceinline__ unsigned short f2b_fast(float f){
  unsigned int u = __builtin_bit_cast(unsigned int, f);
  return (unsigned short)((u + 0x8000u) >> 16);
}
__device__ __forceinline__ float b2f(unsigned short h){
  unsigned int u = ((unsigned int)h) << 16;
  return __builtin_bit_cast(float, u);
}

#define KDIM 1024

// ---------------- fused prep: x cast + 5 LDS-tiled transposes ----------------
__global__ __launch_bounds__(256) void k_prep(
    const float* __restrict__ x,   unsigned short* __restrict__ Xbf,
    const float* __restrict__ fqk, unsigned short* __restrict__ FqkT,
    const float* __restrict__ fv,  unsigned short* __restrict__ FvT,
    const float* __restrict__ rqk, unsigned short* __restrict__ RqkT,
    const float* __restrict__ rv,  unsigned short* __restrict__ RvT,
    const float* __restrict__ wo,  unsigned short* __restrict__ WOT)
{
  __shared__ float tile[32][33];
  int blk = blockIdx.x;
  int tid = threadIdx.x;
  if (blk < 4096){
    int idx = blk * 256 + tid;
    float4 v = ((const float4*)x)[idx];
    us4 o; o.x = f2b(v.x); o.y = f2b(v.y); o.z = f2b(v.z); o.w = f2b(v.w);
    ((us4*)Xbf)[idx] = o;
    return;
  }
  int t = blk - 4096;
  int mid = t >> 10;
  int within = t & 1023;
  const float* src; unsigned short* dst;
  int b, R, C, tr, tc;
  if (mid < 2){
    src = mid == 0 ? fqk : fv;  dst = mid == 0 ? FqkT : FvT;
    R = 1024; C = 128;
    b = within >> 7; int tw = within & 127; tr = tw >> 2; tc = tw & 3;
  } else {
    src = mid == 2 ? rqk : (mid == 3 ? rv : wo);
    dst = mid == 2 ? RqkT : (mid == 3 ? RvT : WOT);
    R = 1024; C = 1024;
    b = 0; tr = within >> 5; tc = within & 31;
  }
  int r = tid >> 3, c0 = (tid & 7) * 4;
  size_t base = (size_t)b * R * C;
  float4 v = *(const float4*)&src[base + (size_t)(tr*32 + r) * C + tc*32 + c0];
  tile[r][c0+0] = v.x; tile[r][c0+1] = v.y; tile[r][c0+2] = v.z; tile[r][c0+3] = v.w;
  __syncthreads();
  us4 o;
  o.x = f2b(tile[c0+0][r]); o.y = f2b(tile[c0+1][r]);
  o.z = f2b(tile[c0+2][r]); o.w = f2b(tile[c0+3][r]);
  *(us4*)&dst[base + (size_t)(tc*32 + r) * R + tr*32 + c0] = o;
}

// fused mix, us4-vectorized: block = 8 bs x 32 r-quads.
__global__ __launch_bounds__(256) void k_mix(const unsigned short* __restrict__ AH,
    const float* __restrict__ fwq, const float* __restrict__ fwk, const float* __restrict__ fwv,
    const float* __restrict__ rwq, const float* __restrict__ rwk, const float* __restrict__ rwv,
    unsigned short* __restrict__ gq, unsigned short* __restrict__ gk, unsigned short* __restrict__ gv){
  int tid = threadIdx.x;
  int lb = tid >> 5, rq = tid & 31;
  int bs = blockIdx.x * 8 + lb;
  const unsigned short* row = AH + (size_t)bs * 2048;
  float fq[8], fk[8], fv8[8], rqw[8], rkw[8], rvw[8];
  #pragma unroll
  for (int n = 0; n < 8; n++){
    fq[n] = fwq[bs*8+n]; fk[n] = fwk[bs*8+n]; fv8[n] = fwv[bs*8+n];
    rqw[n] = rwq[bs*8+n]; rkw[n] = rwk[bs*8+n]; rvw[n] = rwv[bs*8+n];
  }
  float hq[4] = {}, hk[4] = {}, hv[4] = {};
  #pragma unroll
  for (int n = 0; n < 8; n++){
    us4 a = *(const us4*)&row[n*128 + rq*4];
    us4 av = *(const us4*)&row[1024 + n*128 + rq*4];
    #pragma unroll
    for (int j = 0; j < 4; j++){
      float af = b2f(a[j]);
      hq[j] += af * fq[n]; hk[j] += af * fk[n];
      hv[j] += b2f(av[j]) * fv8[n];
    }
  }
  #pragma unroll
  for (int n = 0; n < 8; n++){
    us4 oq, ok, ov;
    #pragma unroll
    for (int j = 0; j < 4; j++){
      oq[j] = f2b(rqw[n] * hq[j]);
      ok[j] = f2b(rkw[n] * hk[j]);
      ov[j] = f2b(rvw[n] * hv[j]);
    }
    *(us4*)&gq[(size_t)bs*1024 + n*128 + rq*4] = oq;
    *(us4*)&gk[(size_t)bs*1024 + n*128 + rq*4] = ok;
    *(us4*)&gv[(size_t)bs*1024 + n*128 + rq*4] = ov;
  }
}

// Vpack [bh][s][64] -> Vtile [bh][t=s/128][dh][128], LDS-tiled coalesced
__global__ __launch_bounds__(256) void k_transpose_v(const unsigned short* __restrict__ Vp,
                                                     unsigned short* __restrict__ Vt){
  __shared__ unsigned short tile[32][36];
  int blk = blockIdx.x;
  int bh = blk >> 7, rem = blk & 127;
  int t = rem >> 3, tl = rem & 7, ts = tl >> 1, td = tl & 1;
  int tid = threadIdx.x;
  int r = tid >> 3, c0 = (tid & 7) * 4;
  us4 v = *(const us4*)&Vp[((size_t)(bh*2048 + t*128 + ts*32 + r)) * 64 + td*32 + c0];
  *(us4*)&tile[r][c0] = v;
  __syncthreads();
  us4 o;
  o.x = tile[c0+0][r]; o.y = tile[c0+1][r]; o.z = tile[c0+2][r]; o.w = tile[c0+3][r];
  *(us4*)&Vt[((size_t)((bh*16 + t)*64 + td*32 + r)) * 128 + ts*32 + c0] = o;
}

// ---------------- GEMM: C[M,ND] = A[M,K] @ Bt[ND,K]^T, bf16 in, f32 acc ----------------
// OUT_MODE: 0 = f32 row-major (direct), 1 = bf16 row-major, 2 = bf16 head-packed.
// For OUT_MODE 1/2 the C-tile is bounced through LDS (reusing the staging buffer)
// and stored as coalesced us8v.

__device__ __forceinline__ void load_lds16(const void* g, void* l){
  __builtin_amdgcn_global_load_lds((const __attribute__((address_space(1))) unsigned int*)g,
                                   (__attribute__((address_space(3))) unsigned int*)l, 16, 0, 0);
}

template<int OUT_MODE, int BN, int ND, int NTILE>
__global__ __launch_bounds__(256) void k_gemm_bt3(
    const unsigned short* __restrict__ A0, const unsigned short* __restrict__ B0, void* __restrict__ C0,
    const unsigned short* __restrict__ A1, const unsigned short* __restrict__ B1, void* __restrict__ C1,
    const unsigned short* __restrict__ A2, const unsigned short* __restrict__ B2, void* __restrict__ C2)
{
  __shared__ unsigned short Sh[2*128*32 + 2*BN*32];
  unsigned short (*Al)[128*32] = (unsigned short(*)[128*32])Sh;
  unsigned short (*Bl)[BN*32]  = (unsigned short(*)[BN*32])(Sh + 2*128*32);
  int nb8 = gridDim.x >> 3;
  int swz = (blockIdx.x & 7) * nb8 + (blockIdx.x >> 3);
  int job = swz / NTILE, bid = swz % NTILE;
  const unsigned short* A  = job == 0 ? A0 : (job == 1 ? A1 : A2);
  const unsigned short* Bt = job == 0 ? B0 : (job == 1 ? B1 : B2);
  void* C = job == 0 ? C0 : (job == 1 ? C1 : C2);
  constexpr int NBX = ND / BN;
  int bx = bid % NBX, by = bid / NBX;
  int m0 = by * 128, n0 = bx * BN;
  int tid = threadIdx.x, wid = tid >> 6, lane = tid & 63, l15 = lane & 15, g = lane >> 4;
  int wr = wid >> 1, wc = wid & 1;
  constexpr int WCN = BN / 2;
  constexpr int NACC = WCN / 16;

  auto stage = [&](int buf, int kt){
    #pragma unroll
    for (int i = 0; i < 2; i++){
      int c = i * 256 + tid;
      load_lds16(A + (size_t)(m0 + (c >> 2)) * KDIM + kt * 32 + (c & 3) * 8,
                 &Al[buf][(i * 256 + wid * 64) * 8]);
    }
    #pragma unroll
    for (int i = 0; i < BN/64; i++){
      int c = i * 256 + tid;
      load_lds16(Bt + (size_t)(n0 + (c >> 2)) * KDIM + kt * 32 + (c & 3) * 8,
                 &Bl[buf][(i * 256 + wid * 64) * 8]);
    }
  };

  f32x4 acc[4][NACC] = {};

  stage(0, 0);
  __syncthreads();
  int cur = 0;
  const int nk = KDIM / 32;
  for (int kt = 0; kt < nk; ++kt){
    if (kt + 1 < nk) stage(cur ^ 1, kt + 1);
    bf16x8 af[4], bfv[NACC];
    #pragma unroll
    for (int mi = 0; mi < 4; mi++)
      af[mi] = *(const bf16x8*)&Al[cur][(wr*64 + mi*16 + l15) * 32 + g * 8];
    #pragma unroll
    for (int ni = 0; ni < NACC; ni++)
      bfv[ni] = *(const bf16x8*)&Bl[cur][(wc*WCN + ni*16 + l15) * 32 + g * 8];
    #pragma unroll
    for (int mi = 0; mi < 4; mi++)
      #pragma unroll
      for (int ni = 0; ni < NACC; ni++)
        acc[mi][ni] = __builtin_amdgcn_mfma_f32_16x16x32_bf16(af[mi], bfv[ni], acc[mi][ni], 0, 0, 0);
    __syncthreads();
    cur ^= 1;
  }

  if constexpr (OUT_MODE == 0){
    #pragma unroll
    for (int mi = 0; mi < 4; mi++)
      #pragma unroll
      for (int reg = 0; reg < 4; reg++){
        int row = m0 + wr*64 + mi*16 + g*4 + reg;
        #pragma unroll
        for (int ni = 0; ni < NACC; ni++){
          int col = n0 + wc*WCN + ni*16 + l15;
          ((float*)C)[(size_t)row * ND + col] = acc[mi][ni][reg];
        }
      }
  } else {
    // LDS-bounce epilogue: Sh reused as flat [128][BN] u16 C-tile (BN=128 -> 32KB, exact fit)
    unsigned short* Cl = Sh;
    #pragma unroll
    for (int mi = 0; mi < 4; mi++)
      #pragma unroll
      for (int reg = 0; reg < 4; reg++){
        int lrow = wr*64 + mi*16 + g*4 + reg;
        #pragma unroll
        for (int ni = 0; ni < NACC; ni++)
          Cl[lrow*BN + wc*WCN + ni*16 + l15] = f2b(acc[mi][ni][reg]);
      }
    __syncthreads();
    constexpr int VPT = (128*BN/8) / 256;   // us8v per thread (8 for BN=128)
    #pragma unroll
    for (int i = 0; i < VPT; i++){
      int idx = i*256 + tid;
      int lrow = idx / (BN/8), c8 = (idx % (BN/8)) * 8;
      us8v v = *(const us8v*)&Cl[lrow*BN + c8];
      int row = m0 + lrow, col = n0 + c8;
      if (OUT_MODE == 1){
        *(us8v*)&((unsigned short*)C)[(size_t)row * ND + col] = v;
      } else {
        int b = row >> 11, s = row & 2047, h = col >> 6, dh = col & 63;
        *(us8v*)&((unsigned short*)C)[(((size_t)(b*16 + h)) * 2048 + s) * 64 + dh] = v;
      }
    }
  }
}

// ---------------- causal flash attention: QBLK=256, 8 waves, chunk=768, dbuf K/V ----------------
// 480 blocks = 8 XCDs x 60 (4 bh x 15 slots each) -> per-XCD L2 holds its 4 heads' K/V.
// Partials (qt>=3) stored bf16-O + f32-l, 33792 B each.
#define PSTR 72
#define PBYTES 33792   // 256*64*2 (O bf16) + 256*4 (l f32), 256-aligned
__global__ __launch_bounds__(512) void k_attn(
    const unsigned short* __restrict__ Qp_, const unsigned short* __restrict__ Kp_,
    const unsigned short* __restrict__ Vt, unsigned short* __restrict__ AO,
    char* __restrict__ Pws)
{
  __shared__ unsigned short Klds[2][4096];
  __shared__ unsigned short Vlds[2][4096];
  __shared__ unsigned short Plds[8][32*PSTR];

  int xb = (blockIdx.x & 7) * 60 + (blockIdx.x >> 3);
  int bh = xb / 15;
  int slot = xb % 15;
  int qt, c;
  if (slot < 3){ qt = slot; c = 0; }
  else if (slot < 9){ int s = slot - 3; qt = 3 + (s >> 1); c = s & 1; }
  else { int s = slot - 9; qt = 6 + (s >= 3 ? 1 : 0); c = (s >= 3) ? s - 3 : s; }
  int nc = qt < 3 ? 1 : (qt < 6 ? 2 : 3);
  int b = bh >> 4, h = bh & 15;
  int q0 = qt * 256;
  int kv_lo = c * 768;
  int kv_hi = min((c + 1) * 768, q0 + 256);
  int niter = (kv_hi - kv_lo) >> 6;

  int tid = threadIdx.x, w = tid >> 6, lane = tid & 63, l15 = lane & 15, g = lane >> 4;
  const unsigned short* Qw = Qp_ + ((size_t)bh * 2048 + q0 + w*32) * 64;
  const unsigned short* Kb = Kp_ + (size_t)bh * 2048 * 64;
  const unsigned short* Vb = Vt + (size_t)bh * 16 * 64 * 128;
  unsigned short* Pw = &Plds[w][0];

  int srow = tid >> 3, sj = tid & 7;

  bf16x8 aq[2][2];
  #pragma unroll
  for (int m = 0; m < 2; m++)
    #pragma unroll
    for (int kk = 0; kk < 2; kk++)
      aq[m][kk] = *(const bf16x8*)(Qw + (m*16 + l15)*64 + kk*32 + g*8);

  const float cs = 0.125f;            // natural-log domain for __expf
  float l_run[2][4] = {};
  f32x4 acc_o[2][4] = {};

  us8v kA, vA, kB, vB;

  auto issue = [&](us8v& k0, us8v& v0, int kv0){
    k0 = *(const us8v*)(Kb + ((size_t)(kv0 + srow)) * 64 + sj*8);
    int t128 = kv0 >> 7, koff = kv0 & 64;
    v0 = *(const us8v*)(Vb + ((size_t)(t128*64 + srow)) * 128 + koff + sj*8);
  };
  auto put = [&](int buf, us8v k0, us8v v0){
    *(us8v*)&Klds[buf][(sj*64 + srow)*8] = k0;
    *(us8v*)&Vlds[buf][(sj*64 + srow)*8] = v0;
  };
  auto compute = [&](int buf, int kv0){
    f32x4 s4[2][4] = {};
    __builtin_amdgcn_s_setprio(1);
    #pragma unroll
    for (int ti = 0; ti < 4; ti++){
      #pragma unroll
      for (int kk = 0; kk < 2; kk++){
        bf16x8 kf = *(const bf16x8*)&Klds[buf][((kk*4 + g)*64 + ti*16 + l15)*8];
        s4[0][ti] = __builtin_amdgcn_mfma_f32_16x16x32_bf16(aq[0][kk], kf, s4[0][ti], 0, 0, 0);
        s4[1][ti] = __builtin_amdgcn_mfma_f32_16x16x32_bf16(aq[1][kk], kf, s4[1][ti], 0, 0, 0);
      }
    }
    __builtin_amdgcn_s_setprio(0);
    bool partial = (kv0 + 64 > q0);
    #pragma unroll
    for (int m = 0; m < 2; m++){
      #pragma unroll
      for (int reg = 0; reg < 4; reg++){
        int row = q0 + w*32 + m*16 + g*4 + reg;
        #pragma unroll
        for (int ti = 0; ti < 4; ti++){
          float x = s4[m][ti][reg] * cs;
          if (partial){
            int col = kv0 + ti*16 + l15;
            if (col > row) x = -1e30f;
          }
          float p = __expf(x);
          l_run[m][reg] += p;
          Pw[(m*16 + g*4 + reg)*PSTR + ((ti ^ g)*16) + l15] = f2b_fast(p);
        }
      }
    }
    bf16x8 pa[2][2];
    #pragma unroll
    for (int m = 0; m < 2; m++)
      #pragma unroll
      for (int cc = 0; cc < 2; cc++){
        int tiL = cc*2 + (g >> 1);
        int tiS = tiL ^ ((l15 >> 2) & 3);
        pa[m][cc] = *(const bf16x8*)&Pw[(m*16 + l15)*PSTR + tiS*16 + (g & 1)*8];
      }
    __builtin_amdgcn_s_setprio(1);
    #pragma unroll
    for (int ni = 0; ni < 4; ni++){
      #pragma unroll
      for (int cc = 0; cc < 2; cc++){
        bf16x8 vf = *(const bf16x8*)&Vlds[buf][((cc*4 + g)*64 + ni*16 + l15)*8];
        acc_o[0][ni] = __builtin_amdgcn_mfma_f32_16x16x32_bf16(pa[0][cc], vf, acc_o[0][ni], 0, 0, 0);
        acc_o[1][ni] = __builtin_amdgcn_mfma_f32_16x16x32_bf16(pa[1][cc], vf, acc_o[1][ni], 0, 0, 0);
      }
    }
    __builtin_amdgcn_s_setprio(0);
  };

  issue(kA, vA, kv_lo);
  put(0, kA, vA);
  __syncthreads();
  int it = 0, cur = 0;
  while (true){
    if (it + 1 < niter) issue(kB, vB, kv_lo + (it+1)*64);
    compute(cur, kv_lo + it*64);
    if (it + 1 < niter) put(cur ^ 1, kB, vB);
    __syncthreads();
    cur ^= 1; ++it;
    if (it >= niter) break;
    if (it + 1 < niter) issue(kA, vA, kv_lo + (it+1)*64);
    compute(cur, kv_lo + it*64);
    if (it + 1 < niter) put(cur ^ 1, kA, vA);
    __syncthreads();
    cur ^= 1; ++it;
    if (it >= niter) break;
  }

  #pragma unroll
  for (int m = 0; m < 2; m++)
    #pragma unroll
    for (int reg = 0; reg < 4; reg++){
      #pragma unroll
      for (int off = 1; off < 16; off <<= 1) l_run[m][reg] += __shfl_xor(l_run[m][reg], off);
    }

  if (nc == 1){
    #pragma unroll
    for (int m = 0; m < 2; m++)
      #pragma unroll
      for (int ni = 0; ni < 4; ni++)
        #pragma unroll
        for (int reg = 0; reg < 4; reg++){
          int row = q0 + w*32 + m*16 + g*4 + reg;
          int dh = ni*16 + l15;
          AO[((size_t)(b*2048 + row)) * 1024 + h*64 + dh] = f2b(acc_o[m][ni][reg] / l_run[m][reg]);
        }
  } else {
    // partial chunk index within this bh: qt 3..5 have 2 chunks, 6..7 have 3
    int poff = (qt < 6) ? (qt - 3) * 2 : 6 + (qt - 6) * 3;
    char* P0 = Pws + ((size_t)(bh*12 + poff + c)) * PBYTES;
    unsigned short* Ob = (unsigned short*)P0;
    float* lb = (float*)(P0 + 32768);
    #pragma unroll
    for (int m = 0; m < 2; m++)
      #pragma unroll
      for (int ni = 0; ni < 4; ni++)
        #pragma unroll
        for (int reg = 0; reg < 4; reg++){
          int lrow = w*32 + m*16 + g*4 + reg;
          Ob[lrow*64 + ni*16 + l15] = f2b(acc_o[m][ni][reg]);
        }
    if (l15 == 0){
      #pragma unroll
      for (int m = 0; m < 2; m++)
        #pragma unroll
        for (int reg = 0; reg < 4; reg++){
          int lrow = w*32 + m*16 + g*4 + reg;
          lb[lrow] = l_run[m][reg];
        }
    }
  }
}

// combine 2-3 chunks for qt >= 3: vectorized, 640 blocks (32bh x 5qt x 4 rowgroups)
__global__ __launch_bounds__(256) void k_attn_reduce(const char* __restrict__ Pws,
                                                     unsigned short* __restrict__ AO){
  int blk = blockIdx.x;
  int rg = blk & 3, tmp = blk >> 2;
  int qtp = tmp % 5, bh = tmp / 5;
  int qt = qtp + 3;
  int b = bh >> 4, h = bh & 15;
  int nc = (qt < 6) ? 2 : 3;
  int poff = (qt < 6) ? (qt - 3) * 2 : 6 + (qt - 6) * 3;
  const char* base = Pws + ((size_t)(bh*12 + poff)) * PBYTES;
  int tid = threadIdx.x;
  int lrow = rg*64 + (tid >> 2);          // 0..255
  int d0 = (tid & 3) * 16;
  float o[16] = {};
  float l = 0.f;
  for (int cc = 0; cc < nc; ++cc){
    const unsigned short* Oc = (const unsigned short*)(base + (size_t)cc*PBYTES);
    const float* lc = (const float*)(base + (size_t)cc*PBYTES + 32768);
    us8v v0 = *(const us8v*)&Oc[lrow*64 + d0];
    us8v v1 = *(const us8v*)&Oc[lrow*64 + d0 + 8];
    #pragma unroll
    for (int j = 0; j < 8; j++){ o[j] += b2f(v0[j]); o[8+j] += b2f(v1[j]); }
    l += lc[lrow];
  }
  float inv = 1.f / l;
  us8v w0, w1;
  #pragma unroll
  for (int j = 0; j < 8; j++){ w0[j] = f2b(o[j]*inv); w1[j] = f2b(o[8+j]*inv); }
  size_t orow = ((size_t)(b*2048 + qt*256 + lrow)) * 1024 + h*64 + d0;
  *(us8v*)&AO[orow] = w0;
  *(us8v*)&AO[orow + 8] = w1;
}

// ---------------- launch ----------------

extern "C" void kernel_launch(void* const* d_in, const int* in_sizes, int n_in,
                              void* d_out, int out_size, void* d_ws, size_t ws_size,
                              hipStream_t stream){
  const float* x    = (const float*)d_in[0];
  const float* fqk  = (const float*)d_in[1];
  const float* fv   = (const float*)d_in[2];
  const float* rqk  = (const float*)d_in[3];
  const float* rv   = (const float*)d_in[4];
  const float* fwQ  = (const float*)d_in[5];
  const float* fwK  = (const float*)d_in[6];
  const float* fwV  = (const float*)d_in[7];
  const float* rwQ  = (const float*)d_in[8];
  const float* rwK  = (const float*)d_in[9];
  const float* rwV  = (const float*)d_in[10];
  const float* wo   = (const float*)d_in[11];
  float* out = (float*)d_out;

  char* ws = (char*)d_ws;
  size_t off = 0;
  auto alloc = [&](size_t bytes)->void*{
    void* p = ws + off; off += (bytes + 255) & ~(size_t)255; return p;
  };
  // weights: FqkT and FvT MUST be contiguous (wide feature GEMM B = [FqkT;FvT])
  unsigned short* FqkT = (unsigned short*)alloc(1024ull*1024*2);
  unsigned short* FvT  = (unsigned short*)alloc(1024ull*1024*2);
  unsigned short* RqkT = (unsigned short*)alloc(1024ull*1024*2);
  unsigned short* RvT  = (unsigned short*)alloc(1024ull*1024*2);
  unsigned short* WOT  = (unsigned short*)alloc(1024ull*1024*2);
  char* overlay = ws + off;
  unsigned short* Xbf  = (unsigned short*)alloc(4096ull*1024*2);
  unsigned short* AHc  = (unsigned short*)alloc(4096ull*2048*2);
  unsigned short* Gq   = (unsigned short*)alloc(4096ull*1024*2);
  unsigned short* Gk   = (unsigned short*)alloc(4096ull*1024*2);
  unsigned short* Gv   = (unsigned short*)alloc(4096ull*1024*2);
  unsigned short* Qp   = (unsigned short*)alloc(4096ull*1024*2);
  unsigned short* Kp   = (unsigned short*)alloc(4096ull*1024*2);
  unsigned short* Vpk  = (unsigned short*)alloc(4096ull*1024*2);
  unsigned short* Vtl  = (unsigned short*)alloc(32ull*16*64*128*2);
  unsigned short* AOm  = (unsigned short*)alloc(4096ull*1024*2);
  char* Pws = overlay;   // 384 partials * 33792 B = 13MB, overlays dead region

  k_prep<<<9216, 256, 0, stream>>>(x, Xbf, fqk, FqkT, fv, FvT, rqk, RqkT, rv, RvT, wo, WOT);

  // wide feature GEMM: AHc[4096][2048] = X @ [FqkT;FvT]^T
  k_gemm_bt3<1,128,2048,512><<<512, 256, 0, stream>>>(Xbf, FqkT, AHc,
                                                      nullptr, nullptr, nullptr,
                                                      nullptr, nullptr, nullptr);
  k_mix<<<512, 256, 0, stream>>>(AHc, fwQ, fwK, fwV, rwQ, rwK, rwV, Gq, Gk, Gv);
  // restore GEMMs -> head-packed Q/K/V (3 jobs x 256 tiles)
  k_gemm_bt3<2,128,1024,256><<<768, 256, 0, stream>>>(Gq, RqkT, Qp, Gk, RqkT, Kp, Gv, RvT, Vpk);
  k_transpose_v<<<4096, 256, 0, stream>>>(Vpk, Vtl);
  // causal flash attention (480 blocks x 512 thr, chunk=768, dbuf)
  k_attn<<<480, 512, 0, stream>>>(Qp, Kp, Vtl, AOm, Pws);
  k_attn_reduce<<<640, 256, 0, stream>>>(Pws, AOm);
  // output projection (BN=64 -> 512 tiles)
  k_gemm_bt3<0,64,1024,512><<<512, 256, 0, stream>>>(AOm, WOT, out,
                                                     nullptr, nullptr, nullptr,
                                                     nullptr, nullptr, nullptr);
}

// Round 15
// 172.703 us; speedup vs baseline: 1.4382x; 1.0163x over previous
//
#include <hip/hip_runtime.h>
#include <stdint.h>

typedef __attribute__((ext_vector_type(8))) __bf16 bf16x8;
typedef __attribute__((ext_vector_type(4))) float f32x4;
typedef __attribute__((ext_vector_type(4))) unsigned short us4;
typedef __attribute__((ext_vector_type(8))) unsigned short us8v;

__device__ __forceinline__ unsigned short f2b(float f){
  unsigned int u = __builtin_bit_cast(unsigned int, f);
  unsigned int r = (u + 0x7fffu + ((u >> 16) & 1u)) >> 16;
  return (unsigned short)r;
}
// fast round-biased f32->bf16 (error <= 2^-9, used for P only)
__device__ __forceinline__ unsigned short f2b_fast(float f){
  unsigned int u = __builtin_bit_cast(unsigned int, f);
  return (unsigned short)((u + 0x8000u) >> 16);
}
__device__ __forceinline__ float b2f(unsigned short h){
  unsigned int u = ((unsigned int)h) << 16;
  return __builtin_bit_cast(float, u);
}

#define KDIM 1024

// ---------------- fused prep: x cast + 5 LDS-tiled transposes ----------------
__global__ __launch_bounds__(256) void k_prep(
    const float* __restrict__ x,   unsigned short* __restrict__ Xbf,
    const float* __restrict__ fqk, unsigned short* __restrict__ FqkT,
    const float* __restrict__ fv,  unsigned short* __restrict__ FvT,
    const float* __restrict__ rqk, unsigned short* __restrict__ RqkT,
    const float* __restrict__ rv,  unsigned short* __restrict__ RvT,
    const float* __restrict__ wo,  unsigned short* __restrict__ WOT)
{
  __shared__ float tile[32][33];
  int blk = blockIdx.x;
  int tid = threadIdx.x;
  if (blk < 4096){
    int idx = blk * 256 + tid;
    float4 v = ((const float4*)x)[idx];
    us4 o; o.x = f2b(v.x); o.y = f2b(v.y); o.z = f2b(v.z); o.w = f2b(v.w);
    ((us4*)Xbf)[idx] = o;
    return;
  }
  int t = blk - 4096;
  int mid = t >> 10;
  int within = t & 1023;
  const float* src; unsigned short* dst;
  int b, R, C, tr, tc;
  if (mid < 2){
    src = mid == 0 ? fqk : fv;  dst = mid == 0 ? FqkT : FvT;
    R = 1024; C = 128;
    b = within >> 7; int tw = within & 127; tr = tw >> 2; tc = tw & 3;
  } else {
    src = mid == 2 ? rqk : (mid == 3 ? rv : wo);
    dst = mid == 2 ? RqkT : (mid == 3 ? RvT : WOT);
    R = 1024; C = 1024;
    b = 0; tr = within >> 5; tc = within & 31;
  }
  int r = tid >> 3, c0 = (tid & 7) * 4;
  size_t base = (size_t)b * R * C;
  float4 v = *(const float4*)&src[base + (size_t)(tr*32 + r) * C + tc*32 + c0];
  tile[r][c0+0] = v.x; tile[r][c0+1] = v.y; tile[r][c0+2] = v.z; tile[r][c0+3] = v.w;
  __syncthreads();
  us4 o;
  o.x = f2b(tile[c0+0][r]); o.y = f2b(tile[c0+1][r]);
  o.z = f2b(tile[c0+2][r]); o.w = f2b(tile[c0+3][r]);
  *(us4*)&dst[base + (size_t)(tc*32 + r) * R + tr*32 + c0] = o;
}

// fused mix, us4-vectorized: block = 8 bs x 32 r-quads.
__global__ __launch_bounds__(256) void k_mix(const unsigned short* __restrict__ AH,
    const float* __restrict__ fwq, const float* __restrict__ fwk, const float* __restrict__ fwv,
    const float* __restrict__ rwq, const float* __restrict__ rwk, const float* __restrict__ rwv,
    unsigned short* __restrict__ gq, unsigned short* __restrict__ gk, unsigned short* __restrict__ gv){
  int tid = threadIdx.x;
  int lb = tid >> 5, rq = tid & 31;
  int bs = blockIdx.x * 8 + lb;
  const unsigned short* row = AH + (size_t)bs * 2048;
  float fq[8], fk[8], fv8[8], rqw[8], rkw[8], rvw[8];
  #pragma unroll
  for (int n = 0; n < 8; n++){
    fq[n] = fwq[bs*8+n]; fk[n] = fwk[bs*8+n]; fv8[n] = fwv[bs*8+n];
    rqw[n] = rwq[bs*8+n]; rkw[n] = rwk[bs*8+n]; rvw[n] = rwv[bs*8+n];
  }
  float hq[4] = {}, hk[4] = {}, hv[4] = {};
  #pragma unroll
  for (int n = 0; n < 8; n++){
    us4 a = *(const us4*)&row[n*128 + rq*4];
    us4 av = *(const us4*)&row[1024 + n*128 + rq*4];
    #pragma unroll
    for (int j = 0; j < 4; j++){
      float af = b2f(a[j]);
      hq[j] += af * fq[n]; hk[j] += af * fk[n];
      hv[j] += b2f(av[j]) * fv8[n];
    }
  }
  #pragma unroll
  for (int n = 0; n < 8; n++){
    us4 oq, ok, ov;
    #pragma unroll
    for (int j = 0; j < 4; j++){
      oq[j] = f2b(rqw[n] * hq[j]);
      ok[j] = f2b(rkw[n] * hk[j]);
      ov[j] = f2b(rvw[n] * hv[j]);
    }
    *(us4*)&gq[(size_t)bs*1024 + n*128 + rq*4] = oq;
    *(us4*)&gk[(size_t)bs*1024 + n*128 + rq*4] = ok;
    *(us4*)&gv[(size_t)bs*1024 + n*128 + rq*4] = ov;
  }
}

// ---------------- GEMM: C[M,ND] = A[M,K] @ Bt[ND,K]^T, bf16 in, f32 acc ----------------
// OUT_MODE: 0 = f32 row-major (direct), 1 = bf16 row-major (LDS bounce),
//           2 = bf16 head-packed [bh][s][64] (LDS bounce),
//           3 = (job-2 only, via OUT_MODE_J2) bf16 V-tile [bh][t128][dh][128]:
//               C-tile written TRANSPOSED into a [128][136] LDS tile, stored coalesced.

__device__ __forceinline__ void load_lds16(const void* g, void* l){
  __builtin_amdgcn_global_load_lds((const __attribute__((address_space(1))) unsigned int*)g,
                                   (__attribute__((address_space(3))) unsigned int*)l, 16, 0, 0);
}

template<int OUT_MODE, int OUT_MODE_J2, int BN, int ND, int NTILE>
__global__ __launch_bounds__(256) void k_gemm_bt3(
    const unsigned short* __restrict__ A0, const unsigned short* __restrict__ B0, void* __restrict__ C0,
    const unsigned short* __restrict__ A1, const unsigned short* __restrict__ B1, void* __restrict__ C1,
    const unsigned short* __restrict__ A2, const unsigned short* __restrict__ B2, void* __restrict__ C2)
{
  constexpr int STAGE_U16 = 2*128*32 + 2*BN*32;
  constexpr int SHSZ = (OUT_MODE_J2 == 3 && STAGE_U16 < 128*136) ? 128*136 : STAGE_U16;
  __shared__ __align__(16) unsigned short Sh[SHSZ];
  unsigned short (*Al)[128*32] = (unsigned short(*)[128*32])Sh;
  unsigned short (*Bl)[BN*32]  = (unsigned short(*)[BN*32])(Sh + 2*128*32);
  int nb8 = gridDim.x >> 3;
  int swz = (blockIdx.x & 7) * nb8 + (blockIdx.x >> 3);
  int job = swz / NTILE, bid = swz % NTILE;
  const unsigned short* A  = job == 0 ? A0 : (job == 1 ? A1 : A2);
  const unsigned short* Bt = job == 0 ? B0 : (job == 1 ? B1 : B2);
  void* C = job == 0 ? C0 : (job == 1 ? C1 : C2);
  constexpr int NBX = ND / BN;
  int bx = bid % NBX, by = bid / NBX;
  int m0 = by * 128, n0 = bx * BN;
  int tid = threadIdx.x, wid = tid >> 6, lane = tid & 63, l15 = lane & 15, g = lane >> 4;
  int wr = wid >> 1, wc = wid & 1;
  constexpr int WCN = BN / 2;
  constexpr int NACC = WCN / 16;

  auto stage = [&](int buf, int kt){
    #pragma unroll
    for (int i = 0; i < 2; i++){
      int c = i * 256 + tid;
      load_lds16(A + (size_t)(m0 + (c >> 2)) * KDIM + kt * 32 + (c & 3) * 8,
                 &Al[buf][(i * 256 + wid * 64) * 8]);
    }
    #pragma unroll
    for (int i = 0; i < BN/64; i++){
      int c = i * 256 + tid;
      load_lds16(Bt + (size_t)(n0 + (c >> 2)) * KDIM + kt * 32 + (c & 3) * 8,
                 &Bl[buf][(i * 256 + wid * 64) * 8]);
    }
  };

  f32x4 acc[4][NACC] = {};

  stage(0, 0);
  __syncthreads();
  int cur = 0;
  const int nk = KDIM / 32;
  for (int kt = 0; kt < nk; ++kt){
    if (kt + 1 < nk) stage(cur ^ 1, kt + 1);
    bf16x8 af[4], bfv[NACC];
    #pragma unroll
    for (int mi = 0; mi < 4; mi++)
      af[mi] = *(const bf16x8*)&Al[cur][(wr*64 + mi*16 + l15) * 32 + g * 8];
    #pragma unroll
    for (int ni = 0; ni < NACC; ni++)
      bfv[ni] = *(const bf16x8*)&Bl[cur][(wc*WCN + ni*16 + l15) * 32 + g * 8];
    #pragma unroll
    for (int mi = 0; mi < 4; mi++)
      #pragma unroll
      for (int ni = 0; ni < NACC; ni++)
        acc[mi][ni] = __builtin_amdgcn_mfma_f32_16x16x32_bf16(af[mi], bfv[ni], acc[mi][ni], 0, 0, 0);
    __syncthreads();
    cur ^= 1;
  }

  if constexpr (OUT_MODE == 0){
    #pragma unroll
    for (int mi = 0; mi < 4; mi++)
      #pragma unroll
      for (int reg = 0; reg < 4; reg++){
        int row = m0 + wr*64 + mi*16 + g*4 + reg;
        #pragma unroll
        for (int ni = 0; ni < NACC; ni++){
          int col = n0 + wc*WCN + ni*16 + l15;
          ((float*)C)[(size_t)row * ND + col] = acc[mi][ni][reg];
        }
      }
  } else {
    if (OUT_MODE_J2 == 3 && job == 2){
      // V-tile epilogue: write transposed [col][136] then store coalesced s-runs.
      unsigned short* Ct = Sh;
      #pragma unroll
      for (int mi = 0; mi < 4; mi++)
        #pragma unroll
        for (int reg = 0; reg < 4; reg++){
          int lrow = wr*64 + mi*16 + g*4 + reg;
          #pragma unroll
          for (int ni = 0; ni < NACC; ni++)
            Ct[(wc*WCN + ni*16 + l15)*136 + lrow] = f2b(acc[mi][ni][reg]);
        }
      __syncthreads();
      int bb = m0 >> 11, t128 = (m0 & 2047) >> 7, h0 = n0 >> 6;
      #pragma unroll
      for (int i = 0; i < 8; i++){
        int flat = i*256 + tid;
        int r = flat >> 4, c8 = (flat & 15) * 8;
        us8v v = *(const us8v*)&Ct[r*136 + c8];
        int h = r >> 6, dh = r & 63;
        int bh = bb*16 + h0 + h;
        *(us8v*)&((unsigned short*)C)[(((size_t)(bh*16 + t128))*64 + dh)*128 + c8] = v;
      }
    } else {
      // LDS-bounce epilogue: Sh reused as flat [128][BN] u16 C-tile
      unsigned short* Cl = Sh;
      #pragma unroll
      for (int mi = 0; mi < 4; mi++)
        #pragma unroll
        for (int reg = 0; reg < 4; reg++){
          int lrow = wr*64 + mi*16 + g*4 + reg;
          #pragma unroll
          for (int ni = 0; ni < NACC; ni++)
            Cl[lrow*BN + wc*WCN + ni*16 + l15] = f2b(acc[mi][ni][reg]);
        }
      __syncthreads();
      constexpr int VPT = (128*BN/8) / 256;
      #pragma unroll
      for (int i = 0; i < VPT; i++){
        int idx = i*256 + tid;
        int lrow = idx / (BN/8), c8 = (idx % (BN/8)) * 8;
        us8v v = *(const us8v*)&Cl[lrow*BN + c8];
        int row = m0 + lrow, col = n0 + c8;
        if (OUT_MODE == 1){
          *(us8v*)&((unsigned short*)C)[(size_t)row * ND + col] = v;
        } else {
          int b = row >> 11, s = row & 2047, h = col >> 6, dh = col & 63;
          *(us8v*)&((unsigned short*)C)[(((size_t)(b*16 + h)) * 2048 + s) * 64 + dh] = v;
        }
      }
    }
  }
}

// ---------------- causal flash attention: QBLK=256, 8 waves, chunk=768, dbuf K/V ----------------
// 480 blocks = 8 XCDs x 60 (4 bh x 15 slots each) -> per-XCD L2 holds its 4 heads' K/V.
// Partials (qt>=3) stored bf16-O + f32-l, 33792 B each.
#define PSTR 72
#define PBYTES 33792   // 256*64*2 (O bf16) + 256*4 (l f32), 256-aligned
__global__ __launch_bounds__(512) void k_attn(
    const unsigned short* __restrict__ Qp_, const unsigned short* __restrict__ Kp_,
    const unsigned short* __restrict__ Vt, unsigned short* __restrict__ AO,
    char* __restrict__ Pws)
{
  __shared__ unsigned short Klds[2][4096];
  __shared__ unsigned short Vlds[2][4096];
  __shared__ unsigned short Plds[8][32*PSTR];

  int xb = (blockIdx.x & 7) * 60 + (blockIdx.x >> 3);
  int bh = xb / 15;
  int slot = xb % 15;
  int qt, c;
  if (slot < 3){ qt = slot; c = 0; }
  else if (slot < 9){ int s = slot - 3; qt = 3 + (s >> 1); c = s & 1; }
  else { int s = slot - 9; qt = 6 + (s >= 3 ? 1 : 0); c = (s >= 3) ? s - 3 : s; }
  int nc = qt < 3 ? 1 : (qt < 6 ? 2 : 3);
  int b = bh >> 4, h = bh & 15;
  int q0 = qt * 256;
  int kv_lo = c * 768;
  int kv_hi = min((c + 1) * 768, q0 + 256);
  int niter = (kv_hi - kv_lo) >> 6;

  int tid = threadIdx.x, w = tid >> 6, lane = tid & 63, l15 = lane & 15, g = lane >> 4;
  const unsigned short* Qw = Qp_ + ((size_t)bh * 2048 + q0 + w*32) * 64;
  const unsigned short* Kb = Kp_ + (size_t)bh * 2048 * 64;
  const unsigned short* Vb = Vt + (size_t)bh * 16 * 64 * 128;
  unsigned short* Pw = &Plds[w][0];

  int srow = tid >> 3, sj = tid & 7;

  bf16x8 aq[2][2];
  #pragma unroll
  for (int m = 0; m < 2; m++)
    #pragma unroll
    for (int kk = 0; kk < 2; kk++)
      aq[m][kk] = *(const bf16x8*)(Qw + (m*16 + l15)*64 + kk*32 + g*8);

  const float cs = 0.125f;            // natural-log domain for __expf
  float l_run[2][4] = {};
  f32x4 acc_o[2][4] = {};

  us8v kA, vA, kB, vB;

  auto issue = [&](us8v& k0, us8v& v0, int kv0){
    k0 = *(const us8v*)(Kb + ((size_t)(kv0 + srow)) * 64 + sj*8);
    int t128 = kv0 >> 7, koff = kv0 & 64;
    v0 = *(const us8v*)(Vb + ((size_t)(t128*64 + srow)) * 128 + koff + sj*8);
  };
  auto put = [&](int buf, us8v k0, us8v v0){
    *(us8v*)&Klds[buf][(sj*64 + srow)*8] = k0;
    *(us8v*)&Vlds[buf][(sj*64 + srow)*8] = v0;
  };
  auto compute = [&](int buf, int kv0){
    f32x4 s4[2][4] = {};
    __builtin_amdgcn_s_setprio(1);
    #pragma unroll
    for (int ti = 0; ti < 4; ti++){
      #pragma unroll
      for (int kk = 0; kk < 2; kk++){
        bf16x8 kf = *(const bf16x8*)&Klds[buf][((kk*4 + g)*64 + ti*16 + l15)*8];
        s4[0][ti] = __builtin_amdgcn_mfma_f32_16x16x32_bf16(aq[0][kk], kf, s4[0][ti], 0, 0, 0);
        s4[1][ti] = __builtin_amdgcn_mfma_f32_16x16x32_bf16(aq[1][kk], kf, s4[1][ti], 0, 0, 0);
      }
    }
    __builtin_amdgcn_s_setprio(0);
    bool partial = (kv0 + 64 > q0);
    #pragma unroll
    for (int m = 0; m < 2; m++){
      #pragma unroll
      for (int reg = 0; reg < 4; reg++){
        int row = q0 + w*32 + m*16 + g*4 + reg;
        #pragma unroll
        for (int ti = 0; ti < 4; ti++){
          float x = s4[m][ti][reg] * cs;
          if (partial){
            int col = kv0 + ti*16 + l15;
            if (col > row) x = -1e30f;
          }
          float p = __expf(x);
          l_run[m][reg] += p;
          Pw[(m*16 + g*4 + reg)*PSTR + ((ti ^ g)*16) + l15] = f2b_fast(p);
        }
      }
    }
    bf16x8 pa[2][2];
    #pragma unroll
    for (int m = 0; m < 2; m++)
      #pragma unroll
      for (int cc = 0; cc < 2; cc++){
        int tiL = cc*2 + (g >> 1);
        int tiS = tiL ^ ((l15 >> 2) & 3);
        pa[m][cc] = *(const bf16x8*)&Pw[(m*16 + l15)*PSTR + tiS*16 + (g & 1)*8];
      }
    __builtin_amdgcn_s_setprio(1);
    #pragma unroll
    for (int ni = 0; ni < 4; ni++){
      #pragma unroll
      for (int cc = 0; cc < 2; cc++){
        bf16x8 vf = *(const bf16x8*)&Vlds[buf][((cc*4 + g)*64 + ni*16 + l15)*8];
        acc_o[0][ni] = __builtin_amdgcn_mfma_f32_16x16x32_bf16(pa[0][cc], vf, acc_o[0][ni], 0, 0, 0);
        acc_o[1][ni] = __builtin_amdgcn_mfma_f32_16x16x32_bf16(pa[1][cc], vf, acc_o[1][ni], 0, 0, 0);
      }
    }
    __builtin_amdgcn_s_setprio(0);
  };

  issue(kA, vA, kv_lo);
  put(0, kA, vA);
  __syncthreads();
  int it = 0, cur = 0;
  while (true){
    if (it + 1 < niter) issue(kB, vB, kv_lo + (it+1)*64);
    compute(cur, kv_lo + it*64);
    if (it + 1 < niter) put(cur ^ 1, kB, vB);
    __syncthreads();
    cur ^= 1; ++it;
    if (it >= niter) break;
    if (it + 1 < niter) issue(kA, vA, kv_lo + (it+1)*64);
    compute(cur, kv_lo + it*64);
    if (it + 1 < niter) put(cur ^ 1, kA, vA);
    __syncthreads();
    cur ^= 1; ++it;
    if (it >= niter) break;
  }

  #pragma unroll
  for (int m = 0; m < 2; m++)
    #pragma unroll
    for (int reg = 0; reg < 4; reg++){
      #pragma unroll
      for (int off = 1; off < 16; off <<= 1) l_run[m][reg] += __shfl_xor(l_run[m][reg], off);
    }

  if (nc == 1){
    #pragma unroll
    for (int m = 0; m < 2; m++)
      #pragma unroll
      for (int ni = 0; ni < 4; ni++)
        #pragma unroll
        for (int reg = 0; reg < 4; reg++){
          int row = q0 + w*32 + m*16 + g*4 + reg;
          int dh = ni*16 + l15;
          AO[((size_t)(b*2048 + row)) * 1024 + h*64 + dh] = f2b(acc_o[m][ni][reg] / l_run[m][reg]);
        }
  } else {
    // partial chunk index within this bh: qt 3..5 have 2 chunks, 6..7 have 3
    int poff = (qt < 6) ? (qt - 3) * 2 : 6 + (qt - 6) * 3;
    char* P0 = Pws + ((size_t)(bh*12 + poff + c)) * PBYTES;
    unsigned short* Ob = (unsigned short*)P0;
    float* lb = (float*)(P0 + 32768);
    #pragma unroll
    for (int m = 0; m < 2; m++)
      #pragma unroll
      for (int ni = 0; ni < 4; ni++)
        #pragma unroll
        for (int reg = 0; reg < 4; reg++){
          int lrow = w*32 + m*16 + g*4 + reg;
          Ob[lrow*64 + ni*16 + l15] = f2b(acc_o[m][ni][reg]);
        }
    if (l15 == 0){
      #pragma unroll
      for (int m = 0; m < 2; m++)
        #pragma unroll
        for (int reg = 0; reg < 4; reg++){
          int lrow = w*32 + m*16 + g*4 + reg;
          lb[lrow] = l_run[m][reg];
        }
    }
  }
}

// combine 2-3 chunks for qt >= 3: vectorized, 640 blocks (32bh x 5qt x 4 rowgroups)
__global__ __launch_bounds__(256) void k_attn_reduce(const char* __restrict__ Pws,
                                                     unsigned short* __restrict__ AO){
  int blk = blockIdx.x;
  int rg = blk & 3, tmp = blk >> 2;
  int qtp = tmp % 5, bh = tmp / 5;
  int qt = qtp + 3;
  int b = bh >> 4, h = bh & 15;
  int nc = (qt < 6) ? 2 : 3;
  int poff = (qt < 6) ? (qt - 3) * 2 : 6 + (qt - 6) * 3;
  const char* base = Pws + ((size_t)(bh*12 + poff)) * PBYTES;
  int tid = threadIdx.x;
  int lrow = rg*64 + (tid >> 2);          // 0..255
  int d0 = (tid & 3) * 16;
  float o[16] = {};
  float l = 0.f;
  for (int cc = 0; cc < nc; ++cc){
    const unsigned short* Oc = (const unsigned short*)(base + (size_t)cc*PBYTES);
    const float* lc = (const float*)(base + (size_t)cc*PBYTES + 32768);
    us8v v0 = *(const us8v*)&Oc[lrow*64 + d0];
    us8v v1 = *(const us8v*)&Oc[lrow*64 + d0 + 8];
    #pragma unroll
    for (int j = 0; j < 8; j++){ o[j] += b2f(v0[j]); o[8+j] += b2f(v1[j]); }
    l += lc[lrow];
  }
  float inv = 1.f / l;
  us8v w0, w1;
  #pragma unroll
  for (int j = 0; j < 8; j++){ w0[j] = f2b(o[j]*inv); w1[j] = f2b(o[8+j]*inv); }
  size_t orow = ((size_t)(b*2048 + qt*256 + lrow)) * 1024 + h*64 + d0;
  *(us8v*)&AO[orow] = w0;
  *(us8v*)&AO[orow + 8] = w1;
}

// ---------------- launch ----------------

extern "C" void kernel_launch(void* const* d_in, const int* in_sizes, int n_in,
                              void* d_out, int out_size, void* d_ws, size_t ws_size,
                              hipStream_t stream){
  const float* x    = (const float*)d_in[0];
  const float* fqk  = (const float*)d_in[1];
  const float* fv   = (const float*)d_in[2];
  const float* rqk  = (const float*)d_in[3];
  const float* rv   = (const float*)d_in[4];
  const float* fwQ  = (const float*)d_in[5];
  const float* fwK  = (const float*)d_in[6];
  const float* fwV  = (const float*)d_in[7];
  const float* rwQ  = (const float*)d_in[8];
  const float* rwK  = (const float*)d_in[9];
  const float* rwV  = (const float*)d_in[10];
  const float* wo   = (const float*)d_in[11];
  float* out = (float*)d_out;

  char* ws = (char*)d_ws;
  size_t off = 0;
  auto alloc = [&](size_t bytes)->void*{
    void* p = ws + off; off += (bytes + 255) & ~(size_t)255; return p;
  };
  // weights: FqkT and FvT MUST be contiguous (wide feature GEMM B = [FqkT;FvT])
  unsigned short* FqkT = (unsigned short*)alloc(1024ull*1024*2);
  unsigned short* FvT  = (unsigned short*)alloc(1024ull*1024*2);
  unsigned short* RqkT = (unsigned short*)alloc(1024ull*1024*2);
  unsigned short* RvT  = (unsigned short*)alloc(1024ull*1024*2);
  unsigned short* WOT  = (unsigned short*)alloc(1024ull*1024*2);
  char* overlay = ws + off;
  unsigned short* Xbf  = (unsigned short*)alloc(4096ull*1024*2);
  unsigned short* AHc  = (unsigned short*)alloc(4096ull*2048*2);
  unsigned short* Gq   = (unsigned short*)alloc(4096ull*1024*2);
  unsigned short* Gk   = (unsigned short*)alloc(4096ull*1024*2);
  unsigned short* Gv   = (unsigned short*)alloc(4096ull*1024*2);
  unsigned short* Qp   = (unsigned short*)alloc(4096ull*1024*2);
  unsigned short* Kp   = (unsigned short*)alloc(4096ull*1024*2);
  unsigned short* Vtl  = (unsigned short*)alloc(32ull*16*64*128*2);
  unsigned short* AOm  = (unsigned short*)alloc(4096ull*1024*2);
  char* Pws = overlay;   // 384 partials * 33792 B = 13MB, overlays dead region

  k_prep<<<9216, 256, 0, stream>>>(x, Xbf, fqk, FqkT, fv, FvT, rqk, RqkT, rv, RvT, wo, WOT);

  // wide feature GEMM: AHc[4096][2048] = X @ [FqkT;FvT]^T
  k_gemm_bt3<1,1,128,2048,512><<<512, 256, 0, stream>>>(Xbf, FqkT, AHc,
                                                        nullptr, nullptr, nullptr,
                                                        nullptr, nullptr, nullptr);
  k_mix<<<512, 256, 0, stream>>>(AHc, fwQ, fwK, fwV, rwQ, rwK, rwV, Gq, Gk, Gv);
  // restore GEMMs -> head-packed Q/K + V-tile direct (3 jobs x 256 tiles)
  k_gemm_bt3<2,3,128,1024,256><<<768, 256, 0, stream>>>(Gq, RqkT, Qp, Gk, RqkT, Kp, Gv, RvT, Vtl);
  // causal flash attention (480 blocks x 512 thr, chunk=768, dbuf)
  k_attn<<<480, 512, 0, stream>>>(Qp, Kp, Vtl, AOm, Pws);
  k_attn_reduce<<<640, 256, 0, stream>>>(Pws, AOm);
  // output projection (BN=64 -> 512 tiles)
  k_gemm_bt3<0,0,64,1024,512><<<512, 256, 0, stream>>>(AOm, WOT, out,
                                                       nullptr, nullptr, nullptr,
                                                       nullptr, nullptr, nullptr);
}